// Round 3
// baseline (407.965 us; speedup 1.0000x reference)
//
#include <hip/hip_runtime.h>

typedef unsigned short u16;
typedef unsigned int uint32;
typedef __attribute__((ext_vector_type(8))) short short8;
typedef __attribute__((ext_vector_type(4))) float float4v;

#define N_NODES 50000
#define N_EDGES 800000
#define N_TOT   850000
#define NBH 256                          // blocks for hist/scatter passes
#define NB_BKT ((N_NODES + 255) >> 8)    // 196 coarse dst-buckets (256 nodes each)
#define NODE_BLOCKS ((N_NODES + 3) / 4)  // 12500: one wave per node

__device__ __forceinline__ float b2f(u16 u) {
  return __uint_as_float(((unsigned int)u) << 16);
}
__device__ __forceinline__ u16 f2b(float f) {
  unsigned int x = __float_as_uint(f);
  unsigned int r = (x + 0x7fffu + ((x >> 16) & 1u)) >> 16;
  return (u16)r;
}
__device__ __forceinline__ float lo_bf(uint32 g) { return __uint_as_float(g << 16); }
__device__ __forceinline__ float hi_bf(uint32 g) { return __uint_as_float(g & 0xffff0000u); }
__device__ __forceinline__ u16 conv_elem(const void* src, int i, int isf32) {
  if (isf32) return f2b(((const float*)src)[i]);
  return ((const u16*)src)[i];
}
__device__ __forceinline__ float lrelu(float a) { return (a >= 0.f) ? a : 0.2f * a; }
// edge_index element i (flat [2,E]); int64 mode reads low word (ids < 2^31)
__device__ __forceinline__ int eget(const int* __restrict__ ei, int i, int isI64) {
  return isI64 ? ei[2 * i] : ei[i];
}

// ---------------- dtype detection ----------------
// flags[0]=1 if float inputs are fp32 (else bf16); flags[1]=1 if edge_index is int64.
__global__ void detect_mode(const u16* __restrict__ x16, const int* __restrict__ ei32,
                            int* __restrict__ flags) {
  __shared__ int sh_f32, sh_i32;
  int tid = threadIdx.x;
  if (tid == 0) { sh_f32 = 0; sh_i32 = 0; }
  __syncthreads();
  int emax = 0;
  for (int i = tid; i < 4096; i += 256) {
    int e = (x16[i] >> 7) & 0xFF;  // bf16 exponent field
    emax = emax > e ? emax : e;
  }
  if (emax >= 140) atomicOr(&sh_f32, 1);           // |v| >= 2^13: impossible for real bf16 N(0,1)
  if (ei32[2 * tid + 1] != 0) atomicOr(&sh_i32, 1); // nonzero odd word => int32 data
  __syncthreads();
  if (tid == 0) { flags[0] = sh_f32; flags[1] = sh_i32 ? 0 : 1; }
}

__global__ void convert_x4(const void* __restrict__ x, const int* __restrict__ flags,
                           u16* __restrict__ out, int n4) {
  int i = blockIdx.x * blockDim.x + threadIdx.x;
  if (i >= n4) return;
  if (flags[0]) {
    float4 v = ((const float4*)x)[i];
    ushort4 o;
    o.x = f2b(v.x); o.y = f2b(v.y); o.z = f2b(v.z); o.w = f2b(v.w);
    ((ushort4*)out)[i] = o;
  } else {
    ((ushort4*)out)[i] = ((const ushort4*)x)[i];
  }
}

// ---------------- W fragment reorder (direct from raw inputs) + att/bias convert ----------
// Wf[t][c][lane][j] = W[c*32 + (lane>>4)*8 + j][t*16 + (lane&15)], zero-padded.
// Tail threads (idx >= 57344) convert the 1063 att/bias elements into wt.
__global__ void reorder_all(const void* W1, const void* W2, const void* W3,
                            const void* a1s, const void* a1d, const void* b1,
                            const void* a2s, const void* a2d, const void* b2,
                            const void* a3s, const void* a3d, const void* b3,
                            const int* __restrict__ flags,
                            u16* __restrict__ Wf1, u16* __restrict__ Wf2,
                            u16* __restrict__ Wf3, u16* __restrict__ wt) {
  int idx = blockIdx.x * blockDim.x + threadIdx.x;
  int f32 = flags[0];
  if (idx < 57344) {
    const void* W; u16* Wf; int NCOLS, li;
    if (idx < 16384)      { W = W1; Wf = Wf1; NCOLS = 128; li = idx; }
    else if (idx < 32768) { W = W2; Wf = Wf2; NCOLS = 128; li = idx - 16384; }
    else                  { W = W3; Wf = Wf3; NCOLS = 188; li = idx - 32768; }
    int j = li & 7;
    int l = (li >> 3) & 63;
    int c = (li >> 9) & 3;
    int t = li >> 11;
    int k = c * 32 + (l >> 4) * 8 + j;
    int n = t * 16 + (l & 15);
    Wf[li] = (n < NCOLS) ? conv_elem(W, k * NCOLS + n, f32) : (u16)0;
  } else {
    int li = idx - 57344;
    const void* src; int off;
    if (li < 128)       { src = a1s; off = 16384; }
    else if (li < 256)  { src = a1d; off = 16512; li -= 128; }
    else if (li < 384)  { src = b1;  off = 16640; li -= 256; }
    else if (li < 512)  { src = a2s; off = 33152; li -= 384; }
    else if (li < 640)  { src = a2d; off = 33280; li -= 512; }
    else if (li < 768)  { src = b2;  off = 33408; li -= 640; }
    else if (li < 956)  { src = a3s; off = 57600; li -= 768; }
    else if (li < 1144) { src = a3d; off = 57788; li -= 956; }
    else if (li < 1191) { src = b3;  off = 57976; li -= 1144; }
    else return;
    wt[off + li] = conv_elem(src, li, f32);
  }
}

// ---------------- CSR build (NO global atomics) ----------------
// Coarse counting-sort by dst-bucket (256 nodes/bucket), all atomics in LDS:
//   pack_hist -> scan_cols -> scan_base -> scatter_coarse -> build_csr.
// build_csr fuses degree-hist, within-bucket scan, row_start, self-loop
// placement, csr_dst runs, and final edge placement (one block per bucket);
// row_start[n] = base[bkt] + bkt*256 + edge_prefix + tid needs no global scan.

// pass 1: pack (dst<<16)|src and per-block LDS histogram of dst>>8.
__global__ __launch_bounds__(256) void pack_hist(const int* __restrict__ ei,
                                                 const int* __restrict__ flags,
                                                 uint32* __restrict__ epack,
                                                 int* __restrict__ cnt, int nE) {
  __shared__ int hist[NB_BKT];
  for (int t = threadIdx.x; t < NB_BKT; t += 256) hist[t] = 0;
  __syncthreads();
  const int i64 = flags[1];
  const int chunk = (nE + NBH - 1) / NBH;
  const int lo = blockIdx.x * chunk;
  const int hi = min(lo + chunk, nE);
  for (int e = lo + (int)threadIdx.x; e < hi; e += 256) {
    int s = eget(ei, e, i64);
    int d = eget(ei, nE + e, i64);
    epack[e] = ((uint32)d << 16) | (uint32)s;
    atomicAdd(&hist[d >> 8], 1);
  }
  __syncthreads();
  for (int t = threadIdx.x; t < NB_BKT; t += 256) cnt[t * NBH + blockIdx.x] = hist[t];
}

// exclusive scan of cnt[bkt][0..NBH) along the block axis (in place) + bucket totals.
__global__ __launch_bounds__(256) void scan_cols(int* __restrict__ cnt,
                                                 int* __restrict__ total) {
  __shared__ int ws[4];
  const int bkt = blockIdx.x;
  const int tid = threadIdx.x, lane = tid & 63, wv = tid >> 6;
  int v = cnt[bkt * NBH + tid];
  int incl = v;
#pragma unroll
  for (int off = 1; off < 64; off <<= 1) {
    int t = __shfl_up(incl, off, 64);
    if (lane >= off) incl += t;
  }
  if (lane == 63) ws[wv] = incl;
  __syncthreads();
  if (tid == 0) {
    int s = 0;
#pragma unroll
    for (int w = 0; w < 4; w++) { int t = ws[w]; ws[w] = s; s += t; }
    total[bkt] = s;
  }
  __syncthreads();
  cnt[bkt * NBH + tid] = ws[wv] + incl - v;
}

// exclusive scan of the 196 bucket totals -> base[0..NB_BKT], base[NB_BKT]=nE.
__global__ __launch_bounds__(256) void scan_base(const int* __restrict__ total,
                                                 int* __restrict__ base) {
  __shared__ int ws[4];
  const int tid = threadIdx.x, lane = tid & 63, wv = tid >> 6;
  int v = (tid < NB_BKT) ? total[tid] : 0;
  int incl = v;
#pragma unroll
  for (int off = 1; off < 64; off <<= 1) {
    int t = __shfl_up(incl, off, 64);
    if (lane >= off) incl += t;
  }
  if (lane == 63) ws[wv] = incl;
  __syncthreads();
  if (tid == 0) {
    int s = 0;
#pragma unroll
    for (int w = 0; w < 4; w++) { int t = ws[w]; ws[w] = s; s += t; }
    base[NB_BKT] = s;
  }
  __syncthreads();
  if (tid < NB_BKT) base[tid] = ws[wv] + incl - v;
}

// pass 2: scatter into bucket-contiguous staging (per-(block,bucket) runs).
__global__ __launch_bounds__(256) void scatter_coarse(const uint32* __restrict__ epack,
                                                      const int* __restrict__ cnt,
                                                      const int* __restrict__ base,
                                                      uint32* __restrict__ staging, int nE) {
  __shared__ int lcur[NB_BKT];
  for (int t = threadIdx.x; t < NB_BKT; t += 256)
    lcur[t] = base[t] + cnt[t * NBH + blockIdx.x];
  __syncthreads();
  const int chunk = (nE + NBH - 1) / NBH;
  const int lo = blockIdx.x * chunk;
  const int hi = min(lo + chunk, nE);
  for (int e = lo + (int)threadIdx.x; e < hi; e += 256) {
    uint32 pk = epack[e];
    int p = atomicAdd(&lcur[pk >> 24], 1);  // bkt = d>>8 = pk>>24
    staging[p] = pk;
  }
}

// pass 3 (fused): per-bucket degree hist + scan + row_start + self-loops +
// csr_dst runs + edge placement. One block per bucket.
__global__ __launch_bounds__(256) void build_csr(const uint32* __restrict__ staging,
                                                 const int* __restrict__ base,
                                                 int* __restrict__ row_start,
                                                 u16* __restrict__ csr_dst,
                                                 u16* __restrict__ csr_src16,
                                                 int* __restrict__ csr_src32, int nN) {
  __shared__ int hist[256];
  __shared__ int cur[256];
  __shared__ int ws[4];
  const int b = blockIdx.x;
  const int tid = threadIdx.x;
  const int lane = tid & 63, wv = tid >> 6;
  hist[tid] = 0;
  __syncthreads();
  const int lo = base[b], hi = base[b + 1];
  for (int i = lo + tid; i < hi; i += 256)
    atomicAdd(&hist[(staging[i] >> 16) & 255], 1);
  __syncthreads();
  int v = hist[tid];
  int incl = v;
#pragma unroll
  for (int off = 1; off < 64; off <<= 1) {
    int t = __shfl_up(incl, off, 64);
    if (lane >= off) incl += t;
  }
  if (lane == 63) ws[wv] = incl;
  __syncthreads();
  if (tid == 0) {
    int s = 0;
#pragma unroll
    for (int w = 0; w < 4; w++) { int t = ws[w]; ws[w] = s; s += t; }
  }
  __syncthreads();
  int excl = ws[wv] + incl - v;
  const int n = (b << 8) + tid;
  if (n < nN) {
    int rs = lo + (b << 8) + excl + tid;  // edges-before + selfloops-before
    row_start[n] = rs;
    csr_src16[rs] = (u16)n;  // self-loop at slot rs
    csr_src32[rs] = n;
    u16 g16 = (u16)n;
    for (int k = 0; k <= v; k++) csr_dst[rs + k] = g16;
    cur[tid] = rs + 1;
  }
  if (b == NB_BKT - 1 && tid == 0) row_start[nN] = N_TOT;
  __syncthreads();
  for (int i = lo + tid; i < hi; i += 256) {
    uint32 pk = staging[i];
    int p = atomicAdd(&cur[(pk >> 16) & 255], 1);
    u16 s = (u16)(pk & 0xffffu);
    csr_src16[p] = s;
    csr_src32[p] = (int)s;
  }
}

// ---------------- MFMA GEMM: H[M,NCOLS] = X[M,128] @ W[128,NCOLS] ----------------
// One wave per 16-row tile. B from fragment-ordered Wf (L2-resident). No LDS.
// AHEAD: A operand is head-major [4][N][32] (k-chunk c = head c's slab).
// HHEAD: store H head-major [4][N][32] (layers 1/2, cols = head*32+c32).
// FUSE_A (layers 1/2): head h owns tiles 2h,2h+1 -> logits in epilogue.
// CMAJOR+FUSE3 (layer 3): class-major store and head-masked logit accumulation.
template <int NT, int NCOLS, int STRIDE, bool FUSE_A, bool CMAJOR, bool FUSE3,
          bool AHEAD, bool HHEAD>
__global__ __launch_bounds__(256) void gemm_mfma(const u16* __restrict__ X,
                                                 const u16* __restrict__ Wf,
                                                 const u16* __restrict__ attS,
                                                 const u16* __restrict__ attD,
                                                 u16* __restrict__ H,
                                                 float* __restrict__ a_s,
                                                 float* __restrict__ a_d, int M) {
  // readfirstlane: prove wave-uniformity of the wave id to the compiler (SGPR loops/addrs)
  const int wid = __builtin_amdgcn_readfirstlane(threadIdx.x >> 6);
  const int lane = threadIdx.x & 63;
  const int row0 = (blockIdx.x * 4 + wid) * 16;
  if (row0 >= M) return;
  const int qr = lane >> 4;   // quad: k-subchunk for A/B, row group for C/D
  const int ln = lane & 15;   // A row within tile / C col within tile

  float4v acc[NT];
#pragma unroll
  for (int t = 0; t < NT; t++) acc[t] = (float4v){0.f, 0.f, 0.f, 0.f};

  const short8* Wf8 = (const short8*)Wf;  // [(t*4 + c)*64 + lane]
  const u16* xrow = AHEAD ? X + (size_t)(row0 + ln) * 32 + qr * 8
                          : X + (size_t)(row0 + ln) * 128 + qr * 8;

#pragma unroll
  for (int c = 0; c < 4; c++) {
    const u16* ap = AHEAD ? xrow + (size_t)c * (N_NODES * 32) : xrow + c * 32;
    short8 afrag = *(const short8*)ap;
#pragma unroll
    for (int t = 0; t < NT; t++) {
      short8 bfrag = Wf8[(t * 4 + c) * 64 + lane];
      acc[t] = __builtin_amdgcn_mfma_f32_16x16x32_bf16(afrag, bfrag, acc[t], 0, 0, 0);
    }
  }

  // store H (D layout: row = qr*4 + i, col = t*16 + ln)
#pragma unroll
  for (int t = 0; t < NT; t++) {
    int col = t * 16 + ln;
    if (col < NCOLS) {
      int off;
      if constexpr (CMAJOR) {
        int h = (col >= 141) ? 3 : (col >= 94) ? 2 : (col >= 47) ? 1 : 0;
        int c = col - h * 47;
        off = c * 4 + h;
      } else {
        off = col;
      }
#pragma unroll
      for (int i = 0; i < 4; i++) {
        int row = row0 + qr * 4 + i;
        if constexpr (HHEAD) {
          H[((size_t)(t >> 1) * N_NODES + row) * 32 + (t & 1) * 16 + ln] = f2b(acc[t][i]);
        } else {
          H[(size_t)row * STRIDE + off] = f2b(acc[t][i]);
        }
      }
    }
  }

  if constexpr (FUSE_A) {
    float aSf[NT], aDf[NT];
#pragma unroll
    for (int t = 0; t < NT; t++) {
      aSf[t] = b2f(attS[t * 16 + ln]);
      aDf[t] = b2f(attD[t * 16 + ln]);
    }
#pragma unroll
    for (int h = 0; h < 4; h++) {
#pragma unroll
      for (int i = 0; i < 4; i++) {
        float s = acc[2 * h][i] * aSf[2 * h] + acc[2 * h + 1][i] * aSf[2 * h + 1];
        float d = acc[2 * h][i] * aDf[2 * h] + acc[2 * h + 1][i] * aDf[2 * h + 1];
#pragma unroll
        for (int m = 1; m < 16; m <<= 1) {
          s += __shfl_xor(s, m, 64);
          d += __shfl_xor(d, m, 64);
        }
        if (ln == 0) {
          int r = row0 + qr * 4 + i;
          a_s[r * 4 + h] = s;
          a_d[r * 4 + h] = d;
        }
      }
    }
  }

  if constexpr (FUSE3) {
    // a_s[n][h] = sum_c H[n][h*47+c] * attS[h*47+c]; col = h*47+c indexes attS directly.
    float sh[4][4], dh[4][4];  // [head][i]
#pragma unroll
    for (int h = 0; h < 4; h++)
#pragma unroll
      for (int i = 0; i < 4; i++) { sh[h][i] = 0.f; dh[h][i] = 0.f; }
#pragma unroll
    for (int t = 0; t < NT; t++) {
      int col = t * 16 + ln;
      bool v = (col < NCOLS);
      float aS = v ? b2f(attS[col]) : 0.f;
      float aD = v ? b2f(attD[col]) : 0.f;
      int hh = (col >= 141) ? 3 : (col >= 94) ? 2 : (col >= 47) ? 1 : 0;
      float aS0 = (hh == 0) ? aS : 0.f, aS1 = (hh == 1) ? aS : 0.f;
      float aS2 = (hh == 2) ? aS : 0.f, aS3 = (hh == 3) ? aS : 0.f;
      float aD0 = (hh == 0) ? aD : 0.f, aD1 = (hh == 1) ? aD : 0.f;
      float aD2 = (hh == 2) ? aD : 0.f, aD3 = (hh == 3) ? aD : 0.f;
#pragma unroll
      for (int i = 0; i < 4; i++) {
        float a = acc[t][i];
        sh[0][i] += a * aS0; sh[1][i] += a * aS1;
        sh[2][i] += a * aS2; sh[3][i] += a * aS3;
        dh[0][i] += a * aD0; dh[1][i] += a * aD1;
        dh[2][i] += a * aD2; dh[3][i] += a * aD3;
      }
    }
#pragma unroll
    for (int h = 0; h < 4; h++) {
#pragma unroll
      for (int i = 0; i < 4; i++) {
        float s = sh[h][i], d = dh[h][i];
#pragma unroll
        for (int m = 1; m < 16; m <<= 1) {
          s += __shfl_xor(s, m, 64);
          d += __shfl_xor(d, m, 64);
        }
        if (ln == 0) {
          int r = row0 + qr * 4 + i;
          a_s[r * 4 + h] = s;
          a_d[r * 4 + h] = d;
        }
      }
    }
  }
}

// ---------------- per-edge softmax weights (unnormalized, packed bf16) ----------------
// w[e][h] = exp(leaky(a_s[src][h] + a_d[dst][h])) as bf16. Self-normalizing: den sums
// the same bf16 values, so ratios carry only ~2^-9 relative error.
// HM: write head-major u16 slabs [4][N_TOT] (layers 1/2); else packed uint2 (layer 3).
template <bool HM>
__global__ __launch_bounds__(256) void edge_weights(const u16* __restrict__ csr_src,
                                                    const u16* __restrict__ csr_dst,
                                                    const float* __restrict__ a_s,
                                                    const float* __restrict__ a_d,
                                                    u16* __restrict__ wout, int nE) {
  int e = blockIdx.x * blockDim.x + threadIdx.x;
  if (e >= nE) return;
  int s = csr_src[e], d = csr_dst[e];
  float4 as = ((const float4*)a_s)[s];
  float4 ad = ((const float4*)a_d)[d];
  float ww0 = __expf(lrelu(as.x + ad.x));
  float ww1 = __expf(lrelu(as.y + ad.y));
  float ww2 = __expf(lrelu(as.z + ad.z));
  float ww3 = __expf(lrelu(as.w + ad.w));
  if constexpr (HM) {
    wout[e] = f2b(ww0);
    wout[N_TOT + e] = f2b(ww1);
    wout[2 * N_TOT + e] = f2b(ww2);
    wout[3 * N_TOT + e] = f2b(ww3);
  } else {
    uint2 o;
    o.x = ((uint32)f2b(ww1) << 16) | (uint32)f2b(ww0);
    o.y = ((uint32)f2b(ww3) << 16) | (uint32)f2b(ww2);
    ((uint2*)wout)[e] = o;
  }
}

// ---------------- aggregation ----------------

// layers 1/2, head-phased: blockIdx = head*12500 + nb; wave per (node, head).
// 8 edge-slots x 8 lanes; per edge one 64B line (uint2 = 4 cols/lane).
// Per phase the hot slab (3.2 MB) fits one XCD L2 -> high hit rate.
__global__ __launch_bounds__(256) void aggregate12_hm(const u16* __restrict__ hH,
                                                      const u16* __restrict__ wH,
                                                      const int* __restrict__ row_start,
                                                      const int* __restrict__ csr_src,
                                                      const u16* __restrict__ bias,
                                                      u16* __restrict__ out, int nN) {
  const int lane = threadIdx.x & 63;
  const int wid = __builtin_amdgcn_readfirstlane(threadIdx.x >> 6);
  const int head = __builtin_amdgcn_readfirstlane(blockIdx.x / NODE_BLOCKS);
  const int nb = blockIdx.x - head * NODE_BLOCKS;
  const int n = nb * 4 + wid;
  if (n >= nN) return;
  const int es = lane >> 3;  // edge slot 0..7
  const int cl = lane & 7;   // uint2 index within 32-col head row
  const uint2* hslab = (const uint2*)(hH + (size_t)head * (N_NODES * 32));
  const u16* wslab = wH + (size_t)head * N_TOT;
  int beg = row_start[n], end = row_start[n + 1];

  float acc0 = 0.f, acc1 = 0.f, acc2 = 0.f, acc3 = 0.f, den = 0.f;
  for (int e = beg; e < end; e += 16) {
    int i0 = e + es, i1 = e + 8 + es;
    bool v0 = i0 < end, v1 = i1 < end;
    int j0 = v0 ? i0 : beg;
    int j1 = v1 ? i1 : beg;
    int s0 = csr_src[j0];
    int s1 = csr_src[j1];
    float w0 = v0 ? b2f(wslab[j0]) : 0.f;
    float w1 = v1 ? b2f(wslab[j1]) : 0.f;
    uint2 g0 = hslab[s0 * 8 + cl];
    uint2 g1 = hslab[s1 * 8 + cl];
    den += w0;
    acc0 += w0 * lo_bf(g0.x); acc1 += w0 * hi_bf(g0.x);
    acc2 += w0 * lo_bf(g0.y); acc3 += w0 * hi_bf(g0.y);
    den += w1;
    acc0 += w1 * lo_bf(g1.x); acc1 += w1 * hi_bf(g1.x);
    acc2 += w1 * lo_bf(g1.y); acc3 += w1 * hi_bf(g1.y);
  }
#pragma unroll
  for (int m = 8; m < 64; m <<= 1) {
    acc0 += __shfl_xor(acc0, m, 64);
    acc1 += __shfl_xor(acc1, m, 64);
    acc2 += __shfl_xor(acc2, m, 64);
    acc3 += __shfl_xor(acc3, m, 64);
    den += __shfl_xor(den, m, 64);
  }
  if (es == 0) {
    float inv = 1.0f / den;
    float b0 = b2f(bias[head * 32 + 4 * cl]);
    float b1 = b2f(bias[head * 32 + 4 * cl + 1]);
    float b2v = b2f(bias[head * 32 + 4 * cl + 2]);
    float b3v = b2f(bias[head * 32 + 4 * cl + 3]);
    float o0 = fmaxf(acc0 * inv + b0, 0.f);  // relu between layers
    float o1 = fmaxf(acc1 * inv + b1, 0.f);
    float o2 = fmaxf(acc2 * inv + b2v, 0.f);
    float o3 = fmaxf(acc3 * inv + b3v, 0.f);
    uint2 pk;
    pk.x = ((uint32)f2b(o1) << 16) | (uint32)f2b(o0);
    pk.y = ((uint32)f2b(o3) << 16) | (uint32)f2b(o2);
    ((uint2*)out)[(size_t)(head * N_NODES + n) * 8 + cl] = pk;
  }
}

// layer 3: class-major h3 (uint2 gather = 4 head vals for class `lane`),
// mean over heads + bias + log_softmax. 8-deep unroll for MLP.
__global__ __launch_bounds__(256) void aggregate3(const u16* __restrict__ h3,
                                                  const uint2* __restrict__ wbuf,
                                                  const int* __restrict__ row_start,
                                                  const int* __restrict__ csr_src,
                                                  const u16* __restrict__ b3,
                                                  const int* __restrict__ flags,
                                                  void* __restrict__ out, int nN) {
  const int lane = threadIdx.x & 63;
  const int wid = __builtin_amdgcn_readfirstlane(threadIdx.x >> 6);  // SGPR wave id
  const int n = blockIdx.x * 4 + wid;
  if (n >= nN) return;
  const bool act = lane < 47;
  const int lidx = act ? lane : 0;
  const float b3v = act ? b2f(b3[lane]) : 0.f;
  const int isf32 = flags[0];
  const uint2* h3v = (const uint2*)h3;  // row = 48 uint2
  int beg = row_start[n], end = row_start[n + 1];

  float den0 = 0.f, den1 = 0.f, den2 = 0.f, den3 = 0.f;
  float acc0 = 0.f, acc1 = 0.f, acc2 = 0.f, acc3 = 0.f;
  int e = beg;
  for (; e + 7 < end; e += 8) {
    int s[8];
    uint2 wp[8];
    uint2 g[8];
#pragma unroll
    for (int j = 0; j < 8; j++) s[j] = csr_src[e + j];
#pragma unroll
    for (int j = 0; j < 8; j++) wp[j] = wbuf[e + j];
#pragma unroll
    for (int j = 0; j < 8; j++) g[j] = h3v[(size_t)s[j] * 48 + lidx];
#pragma unroll
    for (int j = 0; j < 8; j++) {
      float w0 = lo_bf(wp[j].x), w1 = hi_bf(wp[j].x);
      float w2 = lo_bf(wp[j].y), w3 = hi_bf(wp[j].y);
      den0 += w0; den1 += w1; den2 += w2; den3 += w3;
      acc0 += w0 * lo_bf(g[j].x);
      acc1 += w1 * hi_bf(g[j].x);
      acc2 += w2 * lo_bf(g[j].y);
      acc3 += w3 * hi_bf(g[j].y);
    }
  }
  for (; e + 3 < end; e += 4) {
    int s[4];
    uint2 wp[4];
    uint2 g[4];
#pragma unroll
    for (int j = 0; j < 4; j++) s[j] = csr_src[e + j];
#pragma unroll
    for (int j = 0; j < 4; j++) wp[j] = wbuf[e + j];
#pragma unroll
    for (int j = 0; j < 4; j++) g[j] = h3v[(size_t)s[j] * 48 + lidx];
#pragma unroll
    for (int j = 0; j < 4; j++) {
      float w0 = lo_bf(wp[j].x), w1 = hi_bf(wp[j].x);
      float w2 = lo_bf(wp[j].y), w3 = hi_bf(wp[j].y);
      den0 += w0; den1 += w1; den2 += w2; den3 += w3;
      acc0 += w0 * lo_bf(g[j].x);
      acc1 += w1 * hi_bf(g[j].x);
      acc2 += w2 * lo_bf(g[j].y);
      acc3 += w3 * hi_bf(g[j].y);
    }
  }
  for (; e < end; ++e) {
    int s = csr_src[e];
    uint2 wp = wbuf[e];
    uint2 g = h3v[(size_t)s * 48 + lidx];
    float w0 = lo_bf(wp.x), w1 = hi_bf(wp.x);
    float w2 = lo_bf(wp.y), w3 = hi_bf(wp.y);
    den0 += w0; den1 += w1; den2 += w2; den3 += w3;
    acc0 += w0 * lo_bf(g.x);
    acc1 += w1 * hi_bf(g.x);
    acc2 += w2 * lo_bf(g.y);
    acc3 += w3 * hi_bf(g.y);
  }
  float val = act ? 0.25f * (acc0 / den0 + acc1 / den1 + acc2 / den2 + acc3 / den3) + b3v
                  : -1e30f;
  float mx = val;
#pragma unroll
  for (int m = 1; m < 64; m <<= 1) mx = fmaxf(mx, __shfl_xor(mx, m, 64));
  float ex = act ? __expf(val - mx) : 0.f;
  float sm = ex;
#pragma unroll
  for (int m = 1; m < 64; m <<= 1) sm += __shfl_xor(sm, m, 64);
  float lse = mx + __logf(sm);
  if (act) {
    float r = val - lse;
    if (isf32) ((float*)out)[n * 47 + lane] = r;
    else       ((u16*)out)[n * 47 + lane] = f2b(r);
  }
}

// ---------------- launch ----------------

extern "C" void kernel_launch(void* const* d_in, const int* in_sizes, int n_in,
                              void* d_out, int out_size, void* d_ws, size_t ws_size,
                              hipStream_t stream) {
  const void* x   = d_in[0];
  const void* ei  = d_in[1];
  const void* W1  = d_in[2];
  const void* a1s = d_in[3];
  const void* a1d = d_in[4];
  const void* b1  = d_in[5];
  const void* W2  = d_in[6];
  const void* a2s = d_in[7];
  const void* a2d = d_in[8];
  const void* b2  = d_in[9];
  const void* W3  = d_in[10];
  const void* a3s = d_in[11];
  const void* a3d = d_in[12];
  const void* b3  = d_in[13];
  const int* ei32 = (const int*)ei;

  auto au = [](size_t v) { return (v + 255) & ~(size_t)255; };
  char* p = (char*)d_ws;
  int* flags     = (int*)p; p += 256;
  u16* wt        = (u16*)p; p += au((size_t)58023 * 2);
  u16* Wf1       = (u16*)p; p += au((size_t)16384 * 2);
  u16* Wf2       = (u16*)p; p += au((size_t)16384 * 2);
  u16* Wf3       = (u16*)p; p += au((size_t)24576 * 2);
  int* row_start = (int*)p; p += au((size_t)(N_NODES + 1) * 4);
  int* cnt       = (int*)p; p += au((size_t)NB_BKT * NBH * 4);
  int* btotal    = (int*)p; p += au((size_t)NB_BKT * 4);
  int* bbase     = (int*)p; p += au((size_t)(NB_BKT + 1) * 4);
  u16* csr_src16 = (u16*)p; p += au((size_t)N_TOT * 2);
  u16* csr_dst   = (u16*)p; p += au((size_t)N_TOT * 2);
  int* csr_src32 = (int*)p; p += au((size_t)N_TOT * 4);
  u16* wbuf      = (u16*)p; p += au((size_t)N_TOT * 8);  // 4 u16 slabs OR uint2/edge
  float* a_s     = (float*)p; p += au((size_t)N_NODES * 4 * 4);
  float* a_d     = (float*)p; p += au((size_t)N_NODES * 4 * 4);
  u16* x_c       = (u16*)p; p += au((size_t)N_NODES * 128 * 2);
  u16* hA        = (u16*)p; p += au((size_t)N_NODES * 128 * 2);
  u16* h3        = (u16*)p; p += au((size_t)N_NODES * 192 * 2);
  u16* hB        = x_c;  // x_c is dead after layer-1 GEMM; reuse as hB
  // epack/staging alias h3: both consumed before layer 3 writes h3.
  uint32* epack   = (uint32*)h3;               // 3.2 MB
  uint32* staging = (uint32*)(h3 + 1600000);   // next 3.2 MB

  const u16* a1sc = wt + 16384;
  const u16* a1dc = wt + 16512;
  const u16* b1c  = wt + 16640;
  const u16* a2sc = wt + 33152;
  const u16* a2dc = wt + 33280;
  const u16* b2c  = wt + 33408;
  const u16* a3sc = wt + 57600;
  const u16* a3dc = wt + 57788;
  const u16* b3c  = wt + 57976;

  const int gemmBlocks = (N_NODES / 16 + 3) / 4;   // wave per 16-row tile: 782
  const int edgeBlocks = (N_TOT + 255) / 256;

  // dtype detection + normalization (fp32/bf16 floats, int64/int32 edges)
  detect_mode<<<1, 256, 0, stream>>>((const u16*)x, ei32, flags);
  convert_x4<<<(N_NODES * 128 / 4 + 255) / 256, 256, 0, stream>>>(x, flags, x_c,
                                                                  N_NODES * 128 / 4);
  reorder_all<<<229, 256, 0, stream>>>(W1, W2, W3, a1s, a1d, b1, a2s, a2d, b2,
                                       a3s, a3d, b3, flags, Wf1, Wf2, Wf3, wt);

  // CSR build: coarse counting-sort by dst bucket; LDS atomics only.
  pack_hist<<<NBH, 256, 0, stream>>>(ei32, flags, epack, cnt, N_EDGES);
  scan_cols<<<NB_BKT, 256, 0, stream>>>(cnt, btotal);
  scan_base<<<1, 256, 0, stream>>>(btotal, bbase);
  scatter_coarse<<<NBH, 256, 0, stream>>>(epack, cnt, bbase, staging, N_EDGES);
  build_csr<<<NB_BKT, 256, 0, stream>>>(staging, bbase, row_start, csr_dst,
                                        csr_src16, csr_src32, N_NODES);

  // layer 1 (attention logits fused into GEMM epilogue; H stored head-major)
  gemm_mfma<8, 128, 128, true, false, false, false, true><<<gemmBlocks, 256, 0, stream>>>(
      x_c, Wf1, a1sc, a1dc, hA, a_s, a_d, N_NODES);
  edge_weights<true><<<edgeBlocks, 256, 0, stream>>>(csr_src16, csr_dst, a_s, a_d,
                                                     wbuf, N_TOT);
  aggregate12_hm<<<4 * NODE_BLOCKS, 256, 0, stream>>>(hA, wbuf, row_start, csr_src32,
                                                      b1c, hB, N_NODES);

  // layer 2 (A head-major, H head-major)
  gemm_mfma<8, 128, 128, true, false, false, true, true><<<gemmBlocks, 256, 0, stream>>>(
      hB, Wf2, a2sc, a2dc, hA, a_s, a_d, N_NODES);
  edge_weights<true><<<edgeBlocks, 256, 0, stream>>>(csr_src16, csr_dst, a_s, a_d,
                                                     wbuf, N_TOT);
  aggregate12_hm<<<4 * NODE_BLOCKS, 256, 0, stream>>>(hA, wbuf, row_start, csr_src32,
                                                      b2c, hB, N_NODES);

  // layer 3 (A head-major; h3 class-major; logits fused via head-masked reduce)
  gemm_mfma<12, 188, 192, false, true, true, true, false><<<gemmBlocks, 256, 0, stream>>>(
      hB, Wf3, a3sc, a3dc, h3, a_s, a_d, N_NODES);
  edge_weights<false><<<edgeBlocks, 256, 0, stream>>>(csr_src16, csr_dst, a_s, a_d,
                                                      wbuf, N_TOT);
  aggregate3<<<NODE_BLOCKS, 256, 0, stream>>>(h3, (const uint2*)wbuf, row_start,
                                              csr_src32, b3c, flags, d_out, N_NODES);
}

// Round 4
// 323.090 us; speedup vs baseline: 1.2627x; 1.2627x over previous
//
#include <hip/hip_runtime.h>

typedef unsigned short u16;
typedef unsigned int uint32;
typedef __attribute__((ext_vector_type(8))) short short8;
typedef __attribute__((ext_vector_type(4))) float float4v;

#define N_NODES 50000
#define N_EDGES 800000
#define N_TOT   850000
#define NBH 256                          // blocks for hist/scatter passes
#define NB_BKT ((N_NODES + 255) >> 8)    // 196 coarse dst-buckets (256 nodes each)
#define NODE_BLOCKS ((N_NODES + 3) / 4)  // 12500: one wave per node

__device__ __forceinline__ float b2f(u16 u) {
  return __uint_as_float(((unsigned int)u) << 16);
}
__device__ __forceinline__ u16 f2b(float f) {
  unsigned int x = __float_as_uint(f);
  unsigned int r = (x + 0x7fffu + ((x >> 16) & 1u)) >> 16;
  return (u16)r;
}
__device__ __forceinline__ float lo_bf(uint32 g) { return __uint_as_float(g << 16); }
__device__ __forceinline__ float hi_bf(uint32 g) { return __uint_as_float(g & 0xffff0000u); }
__device__ __forceinline__ u16 conv_elem(const void* src, int i, int isf32) {
  if (isf32) return f2b(((const float*)src)[i]);
  return ((const u16*)src)[i];
}
__device__ __forceinline__ float lrelu(float a) { return (a >= 0.f) ? a : 0.2f * a; }
// edge_index element i (flat [2,E]); int64 mode reads low word (ids < 2^31)
__device__ __forceinline__ int eget(const int* __restrict__ ei, int i, int isI64) {
  return isI64 ? ei[2 * i] : ei[i];
}

// ---------------- dtype detection ----------------
// flags[0]=1 if float inputs are fp32 (else bf16); flags[1]=1 if edge_index is int64.
__global__ void detect_mode(const u16* __restrict__ x16, const int* __restrict__ ei32,
                            int* __restrict__ flags) {
  __shared__ int sh_f32, sh_i32;
  int tid = threadIdx.x;
  if (tid == 0) { sh_f32 = 0; sh_i32 = 0; }
  __syncthreads();
  int emax = 0;
  for (int i = tid; i < 4096; i += 256) {
    int e = (x16[i] >> 7) & 0xFF;  // bf16 exponent field
    emax = emax > e ? emax : e;
  }
  if (emax >= 140) atomicOr(&sh_f32, 1);           // |v| >= 2^13: impossible for real bf16 N(0,1)
  if (ei32[2 * tid + 1] != 0) atomicOr(&sh_i32, 1); // nonzero odd word => int32 data
  __syncthreads();
  if (tid == 0) { flags[0] = sh_f32; flags[1] = sh_i32 ? 0 : 1; }
}

__global__ void convert_x4(const void* __restrict__ x, const int* __restrict__ flags,
                           u16* __restrict__ out, int n4) {
  int i = blockIdx.x * blockDim.x + threadIdx.x;
  if (i >= n4) return;
  if (flags[0]) {
    float4 v = ((const float4*)x)[i];
    ushort4 o;
    o.x = f2b(v.x); o.y = f2b(v.y); o.z = f2b(v.z); o.w = f2b(v.w);
    ((ushort4*)out)[i] = o;
  } else {
    ((ushort4*)out)[i] = ((const ushort4*)x)[i];
  }
}

// ---------------- W fragment reorder (direct from raw inputs) + att/bias convert ----------
// Wf[t][c][lane][j] = W[c*32 + (lane>>4)*8 + j][t*16 + (lane&15)], zero-padded.
// Tail threads (idx >= 57344) convert the 1063 att/bias elements into wt.
__global__ void reorder_all(const void* W1, const void* W2, const void* W3,
                            const void* a1s, const void* a1d, const void* b1,
                            const void* a2s, const void* a2d, const void* b2,
                            const void* a3s, const void* a3d, const void* b3,
                            const int* __restrict__ flags,
                            u16* __restrict__ Wf1, u16* __restrict__ Wf2,
                            u16* __restrict__ Wf3, u16* __restrict__ wt) {
  int idx = blockIdx.x * blockDim.x + threadIdx.x;
  int f32 = flags[0];
  if (idx < 57344) {
    const void* W; u16* Wf; int NCOLS, li;
    if (idx < 16384)      { W = W1; Wf = Wf1; NCOLS = 128; li = idx; }
    else if (idx < 32768) { W = W2; Wf = Wf2; NCOLS = 128; li = idx - 16384; }
    else                  { W = W3; Wf = Wf3; NCOLS = 188; li = idx - 32768; }
    int j = li & 7;
    int l = (li >> 3) & 63;
    int c = (li >> 9) & 3;
    int t = li >> 11;
    int k = c * 32 + (l >> 4) * 8 + j;
    int n = t * 16 + (l & 15);
    Wf[li] = (n < NCOLS) ? conv_elem(W, k * NCOLS + n, f32) : (u16)0;
  } else {
    int li = idx - 57344;
    const void* src; int off;
    if (li < 128)       { src = a1s; off = 16384; }
    else if (li < 256)  { src = a1d; off = 16512; li -= 128; }
    else if (li < 384)  { src = b1;  off = 16640; li -= 256; }
    else if (li < 512)  { src = a2s; off = 33152; li -= 384; }
    else if (li < 640)  { src = a2d; off = 33280; li -= 512; }
    else if (li < 768)  { src = b2;  off = 33408; li -= 640; }
    else if (li < 956)  { src = a3s; off = 57600; li -= 768; }
    else if (li < 1144) { src = a3d; off = 57788; li -= 956; }
    else if (li < 1191) { src = b3;  off = 57976; li -= 1144; }
    else return;
    wt[off + li] = conv_elem(src, li, f32);
  }
}

// ---------------- CSR build (NO global atomics) ----------------
// Coarse counting-sort by dst-bucket (256 nodes/bucket), all atomics in LDS:
//   pack_hist -> scan_cols -> scan_base -> scatter_coarse -> build_csr.
// build_csr fuses degree-hist, within-bucket scan, row_start, self-loop
// placement, csr_dst runs, and final edge placement (one block per bucket);
// row_start[n] = base[bkt] + bkt*256 + edge_prefix + tid needs no global scan.

// pass 1: pack (dst<<16)|src and per-block LDS histogram of dst>>8.
__global__ __launch_bounds__(256) void pack_hist(const int* __restrict__ ei,
                                                 const int* __restrict__ flags,
                                                 uint32* __restrict__ epack,
                                                 int* __restrict__ cnt, int nE) {
  __shared__ int hist[NB_BKT];
  for (int t = threadIdx.x; t < NB_BKT; t += 256) hist[t] = 0;
  __syncthreads();
  const int i64 = flags[1];
  const int chunk = (nE + NBH - 1) / NBH;
  const int lo = blockIdx.x * chunk;
  const int hi = min(lo + chunk, nE);
  for (int e = lo + (int)threadIdx.x; e < hi; e += 256) {
    int s = eget(ei, e, i64);
    int d = eget(ei, nE + e, i64);
    epack[e] = ((uint32)d << 16) | (uint32)s;
    atomicAdd(&hist[d >> 8], 1);
  }
  __syncthreads();
  for (int t = threadIdx.x; t < NB_BKT; t += 256) cnt[t * NBH + blockIdx.x] = hist[t];
}

// exclusive scan of cnt[bkt][0..NBH) along the block axis (in place) + bucket totals.
__global__ __launch_bounds__(256) void scan_cols(int* __restrict__ cnt,
                                                 int* __restrict__ total) {
  __shared__ int ws[4];
  const int bkt = blockIdx.x;
  const int tid = threadIdx.x, lane = tid & 63, wv = tid >> 6;
  int v = cnt[bkt * NBH + tid];
  int incl = v;
#pragma unroll
  for (int off = 1; off < 64; off <<= 1) {
    int t = __shfl_up(incl, off, 64);
    if (lane >= off) incl += t;
  }
  if (lane == 63) ws[wv] = incl;
  __syncthreads();
  if (tid == 0) {
    int s = 0;
#pragma unroll
    for (int w = 0; w < 4; w++) { int t = ws[w]; ws[w] = s; s += t; }
    total[bkt] = s;
  }
  __syncthreads();
  cnt[bkt * NBH + tid] = ws[wv] + incl - v;
}

// exclusive scan of the 196 bucket totals -> base[0..NB_BKT], base[NB_BKT]=nE.
__global__ __launch_bounds__(256) void scan_base(const int* __restrict__ total,
                                                 int* __restrict__ base) {
  __shared__ int ws[4];
  const int tid = threadIdx.x, lane = tid & 63, wv = tid >> 6;
  int v = (tid < NB_BKT) ? total[tid] : 0;
  int incl = v;
#pragma unroll
  for (int off = 1; off < 64; off <<= 1) {
    int t = __shfl_up(incl, off, 64);
    if (lane >= off) incl += t;
  }
  if (lane == 63) ws[wv] = incl;
  __syncthreads();
  if (tid == 0) {
    int s = 0;
#pragma unroll
    for (int w = 0; w < 4; w++) { int t = ws[w]; ws[w] = s; s += t; }
    base[NB_BKT] = s;
  }
  __syncthreads();
  if (tid < NB_BKT) base[tid] = ws[wv] + incl - v;
}

// pass 2: scatter into bucket-contiguous staging (per-(block,bucket) runs).
__global__ __launch_bounds__(256) void scatter_coarse(const uint32* __restrict__ epack,
                                                      const int* __restrict__ cnt,
                                                      const int* __restrict__ base,
                                                      uint32* __restrict__ staging, int nE) {
  __shared__ int lcur[NB_BKT];
  for (int t = threadIdx.x; t < NB_BKT; t += 256)
    lcur[t] = base[t] + cnt[t * NBH + blockIdx.x];
  __syncthreads();
  const int chunk = (nE + NBH - 1) / NBH;
  const int lo = blockIdx.x * chunk;
  const int hi = min(lo + chunk, nE);
  for (int e = lo + (int)threadIdx.x; e < hi; e += 256) {
    uint32 pk = epack[e];
    int p = atomicAdd(&lcur[pk >> 24], 1);  // bkt = d>>8 = pk>>24
    staging[p] = pk;
  }
}

// pass 3 (fused): per-bucket degree hist + scan + row_start + self-loops +
// csr_dst runs + edge placement. One block per bucket.
__global__ __launch_bounds__(256) void build_csr(const uint32* __restrict__ staging,
                                                 const int* __restrict__ base,
                                                 int* __restrict__ row_start,
                                                 u16* __restrict__ csr_dst,
                                                 u16* __restrict__ csr_src16,
                                                 int* __restrict__ csr_src32, int nN) {
  __shared__ int hist[256];
  __shared__ int cur[256];
  __shared__ int ws[4];
  const int b = blockIdx.x;
  const int tid = threadIdx.x;
  const int lane = tid & 63, wv = tid >> 6;
  hist[tid] = 0;
  __syncthreads();
  const int lo = base[b], hi = base[b + 1];
  for (int i = lo + tid; i < hi; i += 256)
    atomicAdd(&hist[(staging[i] >> 16) & 255], 1);
  __syncthreads();
  int v = hist[tid];
  int incl = v;
#pragma unroll
  for (int off = 1; off < 64; off <<= 1) {
    int t = __shfl_up(incl, off, 64);
    if (lane >= off) incl += t;
  }
  if (lane == 63) ws[wv] = incl;
  __syncthreads();
  if (tid == 0) {
    int s = 0;
#pragma unroll
    for (int w = 0; w < 4; w++) { int t = ws[w]; ws[w] = s; s += t; }
  }
  __syncthreads();
  int excl = ws[wv] + incl - v;
  const int n = (b << 8) + tid;
  if (n < nN) {
    int rs = lo + (b << 8) + excl + tid;  // edges-before + selfloops-before
    row_start[n] = rs;
    csr_src16[rs] = (u16)n;  // self-loop at slot rs
    csr_src32[rs] = n;
    u16 g16 = (u16)n;
    for (int k = 0; k <= v; k++) csr_dst[rs + k] = g16;
    cur[tid] = rs + 1;
  }
  if (b == NB_BKT - 1 && tid == 0) row_start[nN] = N_TOT;
  __syncthreads();
  for (int i = lo + tid; i < hi; i += 256) {
    uint32 pk = staging[i];
    int p = atomicAdd(&cur[(pk >> 16) & 255], 1);
    u16 s = (u16)(pk & 0xffffu);
    csr_src16[p] = s;
    csr_src32[p] = (int)s;
  }
}

// ---------------- MFMA GEMM: H[M,NCOLS] = X[M,128] @ W[128,NCOLS] ----------------
// One wave per 16-row tile. B from fragment-ordered Wf (L2-resident). No LDS.
// FUSE_A (layers 1/2): head h owns tiles 2h,2h+1 -> logits in epilogue.
// CMAJOR+FUSE3 (layer 3): class-major store and head-masked logit accumulation.
template <int NT, int NCOLS, int STRIDE, bool FUSE_A, bool CMAJOR, bool FUSE3>
__global__ __launch_bounds__(256) void gemm_mfma(const u16* __restrict__ X,
                                                 const u16* __restrict__ Wf,
                                                 const u16* __restrict__ attS,
                                                 const u16* __restrict__ attD,
                                                 u16* __restrict__ H,
                                                 float* __restrict__ a_s,
                                                 float* __restrict__ a_d, int M) {
  // readfirstlane: prove wave-uniformity of the wave id to the compiler (SGPR loops/addrs)
  const int wid = __builtin_amdgcn_readfirstlane(threadIdx.x >> 6);
  const int lane = threadIdx.x & 63;
  const int row0 = (blockIdx.x * 4 + wid) * 16;
  if (row0 >= M) return;
  const int qr = lane >> 4;   // quad: k-subchunk for A/B, row group for C/D
  const int ln = lane & 15;   // A row within tile / C col within tile

  float4v acc[NT];
#pragma unroll
  for (int t = 0; t < NT; t++) acc[t] = (float4v){0.f, 0.f, 0.f, 0.f};

  const short8* Wf8 = (const short8*)Wf;  // [(t*4 + c)*64 + lane]
  const u16* xrow = X + (size_t)(row0 + ln) * 128 + qr * 8;

#pragma unroll
  for (int c = 0; c < 4; c++) {
    short8 afrag = *(const short8*)(xrow + c * 32);
#pragma unroll
    for (int t = 0; t < NT; t++) {
      short8 bfrag = Wf8[(t * 4 + c) * 64 + lane];
      acc[t] = __builtin_amdgcn_mfma_f32_16x16x32_bf16(afrag, bfrag, acc[t], 0, 0, 0);
    }
  }

  // store H (D layout: row = qr*4 + i, col = t*16 + ln)
#pragma unroll
  for (int t = 0; t < NT; t++) {
    int col = t * 16 + ln;
    if (col < NCOLS) {
      int off;
      if constexpr (CMAJOR) {
        int h = (col >= 141) ? 3 : (col >= 94) ? 2 : (col >= 47) ? 1 : 0;
        int c = col - h * 47;
        off = c * 4 + h;
      } else {
        off = col;
      }
#pragma unroll
      for (int i = 0; i < 4; i++) {
        H[(size_t)(row0 + qr * 4 + i) * STRIDE + off] = f2b(acc[t][i]);
      }
    }
  }

  if constexpr (FUSE_A) {
    float aSf[NT], aDf[NT];
#pragma unroll
    for (int t = 0; t < NT; t++) {
      aSf[t] = b2f(attS[t * 16 + ln]);
      aDf[t] = b2f(attD[t * 16 + ln]);
    }
#pragma unroll
    for (int h = 0; h < 4; h++) {
#pragma unroll
      for (int i = 0; i < 4; i++) {
        float s = acc[2 * h][i] * aSf[2 * h] + acc[2 * h + 1][i] * aSf[2 * h + 1];
        float d = acc[2 * h][i] * aDf[2 * h] + acc[2 * h + 1][i] * aDf[2 * h + 1];
#pragma unroll
        for (int m = 1; m < 16; m <<= 1) {
          s += __shfl_xor(s, m, 64);
          d += __shfl_xor(d, m, 64);
        }
        if (ln == 0) {
          int r = row0 + qr * 4 + i;
          a_s[r * 4 + h] = s;
          a_d[r * 4 + h] = d;
        }
      }
    }
  }

  if constexpr (FUSE3) {
    // a_s[n][h] = sum_c H[n][h*47+c] * attS[h*47+c]; col = h*47+c indexes attS directly.
    float sh[4][4], dh[4][4];  // [head][i]
#pragma unroll
    for (int h = 0; h < 4; h++)
#pragma unroll
      for (int i = 0; i < 4; i++) { sh[h][i] = 0.f; dh[h][i] = 0.f; }
#pragma unroll
    for (int t = 0; t < NT; t++) {
      int col = t * 16 + ln;
      bool v = (col < NCOLS);
      float aS = v ? b2f(attS[col]) : 0.f;
      float aD = v ? b2f(attD[col]) : 0.f;
      int hh = (col >= 141) ? 3 : (col >= 94) ? 2 : (col >= 47) ? 1 : 0;
      float aS0 = (hh == 0) ? aS : 0.f, aS1 = (hh == 1) ? aS : 0.f;
      float aS2 = (hh == 2) ? aS : 0.f, aS3 = (hh == 3) ? aS : 0.f;
      float aD0 = (hh == 0) ? aD : 0.f, aD1 = (hh == 1) ? aD : 0.f;
      float aD2 = (hh == 2) ? aD : 0.f, aD3 = (hh == 3) ? aD : 0.f;
#pragma unroll
      for (int i = 0; i < 4; i++) {
        float a = acc[t][i];
        sh[0][i] += a * aS0; sh[1][i] += a * aS1;
        sh[2][i] += a * aS2; sh[3][i] += a * aS3;
        dh[0][i] += a * aD0; dh[1][i] += a * aD1;
        dh[2][i] += a * aD2; dh[3][i] += a * aD3;
      }
    }
#pragma unroll
    for (int h = 0; h < 4; h++) {
#pragma unroll
      for (int i = 0; i < 4; i++) {
        float s = sh[h][i], d = dh[h][i];
#pragma unroll
        for (int m = 1; m < 16; m <<= 1) {
          s += __shfl_xor(s, m, 64);
          d += __shfl_xor(d, m, 64);
        }
        if (ln == 0) {
          int r = row0 + qr * 4 + i;
          a_s[r * 4 + h] = s;
          a_d[r * 4 + h] = d;
        }
      }
    }
  }
}

// ---------------- per-edge softmax weights for layer 3 (unnormalized, packed bf16x4) ----
// w[e][h] = exp(leaky(a_s[src][h] + a_d[dst][h])) as bf16. Self-normalizing: den sums
// the same bf16 values, so ratios carry only ~2^-9 relative error.
__global__ __launch_bounds__(256) void edge_weights(const u16* __restrict__ csr_src,
                                                    const u16* __restrict__ csr_dst,
                                                    const float* __restrict__ a_s,
                                                    const float* __restrict__ a_d,
                                                    uint2* __restrict__ w, int nE) {
  int e = blockIdx.x * blockDim.x + threadIdx.x;
  if (e >= nE) return;
  int s = csr_src[e], d = csr_dst[e];
  float4 as = ((const float4*)a_s)[s];
  float4 ad = ((const float4*)a_d)[d];
  float w0 = __expf(lrelu(as.x + ad.x));
  float w1 = __expf(lrelu(as.y + ad.y));
  float w2 = __expf(lrelu(as.z + ad.z));
  float w3 = __expf(lrelu(as.w + ad.w));
  uint2 o;
  o.x = ((uint32)f2b(w1) << 16) | (uint32)f2b(w0);
  o.y = ((uint32)f2b(w3) << 16) | (uint32)f2b(w2);
  w[e] = o;
}

// ---------------- aggregation (one node per wave; wave-uniform scalar metadata) ----------

// layers 1/2: lane L owns cols 2L,2L+1 (head L>>4). One uint gather/edge/lane.
// Edge weights computed INLINE (fp32): per edge, lane loads a_s[s*4+hL] (4B
// broadcast from the L2-resident 800KB logit table) + wave-uniform a_d[n*4+hL],
// then exp(lrelu(.)). Replaces the separate edge_weights pass + wbuf round-trip.
// num and den use the same w values -> self-normalizing, numerics preserved.
__global__ __launch_bounds__(256) void aggregate12(const u16* __restrict__ h,
                                                   const float* __restrict__ a_s,
                                                   const float* __restrict__ a_d,
                                                   const int* __restrict__ row_start,
                                                   const int* __restrict__ csr_src,
                                                   const u16* __restrict__ bias,
                                                   u16* __restrict__ out, int nN) {
  const int lane = threadIdx.x & 63;
  const int wid = __builtin_amdgcn_readfirstlane(threadIdx.x >> 6);  // SGPR wave id
  const int n = blockIdx.x * 4 + wid;
  if (n >= nN) return;
  const int hL = lane >> 4;  // head of cols 2L, 2L+1
  const uint32* h32 = (const uint32*)h;
  const float bias0 = b2f(bias[2 * lane]);
  const float bias1 = b2f(bias[2 * lane + 1]);
  const float adv = a_d[n * 4 + hL];  // wave-row uniform, per head group
  int beg = row_start[n], end = row_start[n + 1];

  float acc0 = 0.f, acc1 = 0.f, den = 0.f;
  int e = beg;
  for (; e + 3 < end; e += 4) {
    int s[4];
    float av[4];
    uint32 g[4];
#pragma unroll
    for (int j = 0; j < 4; j++) s[j] = csr_src[e + j];
#pragma unroll
    for (int j = 0; j < 4; j++) av[j] = a_s[s[j] * 4 + hL];
#pragma unroll
    for (int j = 0; j < 4; j++) g[j] = h32[s[j] * 64 + lane];
#pragma unroll
    for (int j = 0; j < 4; j++) {
      float w = __expf(lrelu(av[j] + adv));
      den += w;
      acc0 += w * lo_bf(g[j]);
      acc1 += w * hi_bf(g[j]);
    }
  }
  for (; e < end; ++e) {
    int s = csr_src[e];
    float w = __expf(lrelu(a_s[s * 4 + hL] + adv));
    uint32 g = h32[s * 64 + lane];
    den += w;
    acc0 += w * lo_bf(g);
    acc1 += w * hi_bf(g);
  }
  float inv = 1.0f / den;
  float o0 = fmaxf(acc0 * inv + bias0, 0.f);  // relu between layers
  float o1 = fmaxf(acc1 * inv + bias1, 0.f);
  uint32 packed = ((uint32)f2b(o1) << 16) | (uint32)f2b(o0);
  ((uint32*)out)[n * 64 + lane] = packed;
}

// layer 3: class-major h3 (uint2 gather = 4 head vals for class `lane`),
// mean over heads + bias + log_softmax. 8-deep unroll for MLP.
__global__ __launch_bounds__(256) void aggregate3(const u16* __restrict__ h3,
                                                  const uint2* __restrict__ wbuf,
                                                  const int* __restrict__ row_start,
                                                  const int* __restrict__ csr_src,
                                                  const u16* __restrict__ b3,
                                                  const int* __restrict__ flags,
                                                  void* __restrict__ out, int nN) {
  const int lane = threadIdx.x & 63;
  const int wid = __builtin_amdgcn_readfirstlane(threadIdx.x >> 6);  // SGPR wave id
  const int n = blockIdx.x * 4 + wid;
  if (n >= nN) return;
  const bool act = lane < 47;
  const int lidx = act ? lane : 0;
  const float b3v = act ? b2f(b3[lane]) : 0.f;
  const int isf32 = flags[0];
  const uint2* h3v = (const uint2*)h3;  // row = 48 uint2
  int beg = row_start[n], end = row_start[n + 1];

  float den0 = 0.f, den1 = 0.f, den2 = 0.f, den3 = 0.f;
  float acc0 = 0.f, acc1 = 0.f, acc2 = 0.f, acc3 = 0.f;
  int e = beg;
  for (; e + 7 < end; e += 8) {
    int s[8];
    uint2 wp[8];
    uint2 g[8];
#pragma unroll
    for (int j = 0; j < 8; j++) s[j] = csr_src[e + j];
#pragma unroll
    for (int j = 0; j < 8; j++) wp[j] = wbuf[e + j];
#pragma unroll
    for (int j = 0; j < 8; j++) g[j] = h3v[(size_t)s[j] * 48 + lidx];
#pragma unroll
    for (int j = 0; j < 8; j++) {
      float w0 = lo_bf(wp[j].x), w1 = hi_bf(wp[j].x);
      float w2 = lo_bf(wp[j].y), w3 = hi_bf(wp[j].y);
      den0 += w0; den1 += w1; den2 += w2; den3 += w3;
      acc0 += w0 * lo_bf(g[j].x);
      acc1 += w1 * hi_bf(g[j].x);
      acc2 += w2 * lo_bf(g[j].y);
      acc3 += w3 * hi_bf(g[j].y);
    }
  }
  for (; e + 3 < end; e += 4) {
    int s[4];
    uint2 wp[4];
    uint2 g[4];
#pragma unroll
    for (int j = 0; j < 4; j++) s[j] = csr_src[e + j];
#pragma unroll
    for (int j = 0; j < 4; j++) wp[j] = wbuf[e + j];
#pragma unroll
    for (int j = 0; j < 4; j++) g[j] = h3v[(size_t)s[j] * 48 + lidx];
#pragma unroll
    for (int j = 0; j < 4; j++) {
      float w0 = lo_bf(wp[j].x), w1 = hi_bf(wp[j].x);
      float w2 = lo_bf(wp[j].y), w3 = hi_bf(wp[j].y);
      den0 += w0; den1 += w1; den2 += w2; den3 += w3;
      acc0 += w0 * lo_bf(g[j].x);
      acc1 += w1 * hi_bf(g[j].x);
      acc2 += w2 * lo_bf(g[j].y);
      acc3 += w3 * hi_bf(g[j].y);
    }
  }
  for (; e < end; ++e) {
    int s = csr_src[e];
    uint2 wp = wbuf[e];
    uint2 g = h3v[(size_t)s * 48 + lidx];
    float w0 = lo_bf(wp.x), w1 = hi_bf(wp.x);
    float w2 = lo_bf(wp.y), w3 = hi_bf(wp.y);
    den0 += w0; den1 += w1; den2 += w2; den3 += w3;
    acc0 += w0 * lo_bf(g.x);
    acc1 += w1 * hi_bf(g.x);
    acc2 += w2 * lo_bf(g.y);
    acc3 += w3 * hi_bf(g.y);
  }
  float val = act ? 0.25f * (acc0 / den0 + acc1 / den1 + acc2 / den2 + acc3 / den3) + b3v
                  : -1e30f;
  float mx = val;
#pragma unroll
  for (int m = 1; m < 64; m <<= 1) mx = fmaxf(mx, __shfl_xor(mx, m, 64));
  float ex = act ? __expf(val - mx) : 0.f;
  float sm = ex;
#pragma unroll
  for (int m = 1; m < 64; m <<= 1) sm += __shfl_xor(sm, m, 64);
  float lse = mx + __logf(sm);
  if (act) {
    float r = val - lse;
    if (isf32) ((float*)out)[n * 47 + lane] = r;
    else       ((u16*)out)[n * 47 + lane] = f2b(r);
  }
}

// ---------------- launch ----------------

extern "C" void kernel_launch(void* const* d_in, const int* in_sizes, int n_in,
                              void* d_out, int out_size, void* d_ws, size_t ws_size,
                              hipStream_t stream) {
  const void* x   = d_in[0];
  const void* ei  = d_in[1];
  const void* W1  = d_in[2];
  const void* a1s = d_in[3];
  const void* a1d = d_in[4];
  const void* b1  = d_in[5];
  const void* W2  = d_in[6];
  const void* a2s = d_in[7];
  const void* a2d = d_in[8];
  const void* b2  = d_in[9];
  const void* W3  = d_in[10];
  const void* a3s = d_in[11];
  const void* a3d = d_in[12];
  const void* b3  = d_in[13];
  const int* ei32 = (const int*)ei;

  auto au = [](size_t v) { return (v + 255) & ~(size_t)255; };
  char* p = (char*)d_ws;
  int* flags     = (int*)p; p += 256;
  u16* wt        = (u16*)p; p += au((size_t)58023 * 2);
  u16* Wf1       = (u16*)p; p += au((size_t)16384 * 2);
  u16* Wf2       = (u16*)p; p += au((size_t)16384 * 2);
  u16* Wf3       = (u16*)p; p += au((size_t)24576 * 2);
  int* row_start = (int*)p; p += au((size_t)(N_NODES + 1) * 4);
  int* cnt       = (int*)p; p += au((size_t)NB_BKT * NBH * 4);
  int* btotal    = (int*)p; p += au((size_t)NB_BKT * 4);
  int* bbase     = (int*)p; p += au((size_t)(NB_BKT + 1) * 4);
  u16* csr_src16 = (u16*)p; p += au((size_t)N_TOT * 2);
  u16* csr_dst   = (u16*)p; p += au((size_t)N_TOT * 2);
  int* csr_src32 = (int*)p; p += au((size_t)N_TOT * 4);
  uint2* wbuf    = (uint2*)p; p += au((size_t)N_TOT * 8);
  float* a_s     = (float*)p; p += au((size_t)N_NODES * 4 * 4);
  float* a_d     = (float*)p; p += au((size_t)N_NODES * 4 * 4);
  u16* x_c       = (u16*)p; p += au((size_t)N_NODES * 128 * 2);
  u16* hA        = (u16*)p; p += au((size_t)N_NODES * 128 * 2);
  u16* h3        = (u16*)p; p += au((size_t)N_NODES * 192 * 2);
  u16* hB        = x_c;  // x_c is dead after layer-1 GEMM; reuse as hB
  // epack/staging alias h3: both consumed before layer 3 writes h3.
  uint32* epack   = (uint32*)h3;               // 3.2 MB
  uint32* staging = (uint32*)(h3 + 1600000);   // next 3.2 MB

  const u16* a1sc = wt + 16384;
  const u16* a1dc = wt + 16512;
  const u16* b1c  = wt + 16640;
  const u16* a2sc = wt + 33152;
  const u16* a2dc = wt + 33280;
  const u16* b2c  = wt + 33408;
  const u16* a3sc = wt + 57600;
  const u16* a3dc = wt + 57788;
  const u16* b3c  = wt + 57976;

  const int gemmBlocks = (N_NODES / 16 + 3) / 4;   // wave per 16-row tile: 782
  const int edgeBlocks = (N_TOT + 255) / 256;

  // dtype detection + normalization (fp32/bf16 floats, int64/int32 edges)
  detect_mode<<<1, 256, 0, stream>>>((const u16*)x, ei32, flags);
  convert_x4<<<(N_NODES * 128 / 4 + 255) / 256, 256, 0, stream>>>(x, flags, x_c,
                                                                  N_NODES * 128 / 4);
  reorder_all<<<229, 256, 0, stream>>>(W1, W2, W3, a1s, a1d, b1, a2s, a2d, b2,
                                       a3s, a3d, b3, flags, Wf1, Wf2, Wf3, wt);

  // CSR build: coarse counting-sort by dst bucket; LDS atomics only.
  pack_hist<<<NBH, 256, 0, stream>>>(ei32, flags, epack, cnt, N_EDGES);
  scan_cols<<<NB_BKT, 256, 0, stream>>>(cnt, btotal);
  scan_base<<<1, 256, 0, stream>>>(btotal, bbase);
  scatter_coarse<<<NBH, 256, 0, stream>>>(epack, cnt, bbase, staging, N_EDGES);
  build_csr<<<NB_BKT, 256, 0, stream>>>(staging, bbase, row_start, csr_dst,
                                        csr_src16, csr_src32, N_NODES);

  // layer 1 (attention logits fused into GEMM epilogue; weights fused into aggregate)
  gemm_mfma<8, 128, 128, true, false, false><<<gemmBlocks, 256, 0, stream>>>(
      x_c, Wf1, a1sc, a1dc, hA, a_s, a_d, N_NODES);
  aggregate12<<<NODE_BLOCKS, 256, 0, stream>>>(hA, a_s, a_d, row_start, csr_src32,
                                               b1c, hB, N_NODES);

  // layer 2
  gemm_mfma<8, 128, 128, true, false, false><<<gemmBlocks, 256, 0, stream>>>(
      hB, Wf2, a2sc, a2dc, hA, a_s, a_d, N_NODES);
  aggregate12<<<NODE_BLOCKS, 256, 0, stream>>>(hA, a_s, a_d, row_start, csr_src32,
                                               b2c, hB, N_NODES);

  // layer 3 (h3 class-major; logits fused into GEMM epilogue via head-masked reduce)
  gemm_mfma<12, 188, 192, false, true, true><<<gemmBlocks, 256, 0, stream>>>(
      hB, Wf3, a3sc, a3dc, h3, a_s, a_d, N_NODES);
  edge_weights<<<edgeBlocks, 256, 0, stream>>>(csr_src16, csr_dst, a_s, a_d, wbuf, N_TOT);
  aggregate3<<<NODE_BLOCKS, 256, 0, stream>>>(h3, wbuf, row_start, csr_src32, b3c, flags,
                                              d_out, N_NODES);
}

// Round 5
// 321.473 us; speedup vs baseline: 1.2690x; 1.0050x over previous
//
#include <hip/hip_runtime.h>

typedef unsigned short u16;
typedef unsigned int uint32;
typedef __attribute__((ext_vector_type(8))) short short8;
typedef __attribute__((ext_vector_type(4))) float float4v;

#define N_NODES 50000
#define N_EDGES 800000
#define N_TOT   850000
#define NBH 256                          // blocks for hist/scatter passes
#define NB_BKT ((N_NODES + 255) >> 8)    // 196 coarse dst-buckets (256 nodes each)
#define NODE_BLOCKS ((N_NODES + 3) / 4)  // 12500: one wave per node

__device__ __forceinline__ float b2f(u16 u) {
  return __uint_as_float(((unsigned int)u) << 16);
}
__device__ __forceinline__ u16 f2b(float f) {
  unsigned int x = __float_as_uint(f);
  unsigned int r = (x + 0x7fffu + ((x >> 16) & 1u)) >> 16;
  return (u16)r;
}
__device__ __forceinline__ float lo_bf(uint32 g) { return __uint_as_float(g << 16); }
__device__ __forceinline__ float hi_bf(uint32 g) { return __uint_as_float(g & 0xffff0000u); }
__device__ __forceinline__ u16 conv_elem(const void* src, int i, int isf32) {
  if (isf32) return f2b(((const float*)src)[i]);
  return ((const u16*)src)[i];
}
__device__ __forceinline__ float lrelu(float a) { return (a >= 0.f) ? a : 0.2f * a; }
// edge_index element i (flat [2,E]); int64 mode reads low word (ids < 2^31)
__device__ __forceinline__ int eget(const int* __restrict__ ei, int i, int isI64) {
  return isI64 ? ei[2 * i] : ei[i];
}

// ---------------- dtype detection ----------------
// flags[0]=1 if float inputs are fp32 (else bf16); flags[1]=1 if edge_index is int64.
__global__ void detect_mode(const u16* __restrict__ x16, const int* __restrict__ ei32,
                            int* __restrict__ flags) {
  __shared__ int sh_f32, sh_i32;
  int tid = threadIdx.x;
  if (tid == 0) { sh_f32 = 0; sh_i32 = 0; }
  __syncthreads();
  int emax = 0;
  for (int i = tid; i < 4096; i += 256) {
    int e = (x16[i] >> 7) & 0xFF;  // bf16 exponent field
    emax = emax > e ? emax : e;
  }
  if (emax >= 140) atomicOr(&sh_f32, 1);           // |v| >= 2^13: impossible for real bf16 N(0,1)
  if (ei32[2 * tid + 1] != 0) atomicOr(&sh_i32, 1); // nonzero odd word => int32 data
  __syncthreads();
  if (tid == 0) { flags[0] = sh_f32; flags[1] = sh_i32 ? 0 : 1; }
}

// ---------------- W fragment reorder (direct from raw inputs) + att/bias convert ----------
// Wf[t][c][lane][j] = W[c*32 + (lane>>4)*8 + j][t*16 + (lane&15)], zero-padded.
// Tail threads (idx >= 57344) convert the 1063 att/bias elements into wt.
__global__ void reorder_all(const void* W1, const void* W2, const void* W3,
                            const void* a1s, const void* a1d, const void* b1,
                            const void* a2s, const void* a2d, const void* b2,
                            const void* a3s, const void* a3d, const void* b3,
                            const int* __restrict__ flags,
                            u16* __restrict__ Wf1, u16* __restrict__ Wf2,
                            u16* __restrict__ Wf3, u16* __restrict__ wt) {
  int idx = blockIdx.x * blockDim.x + threadIdx.x;
  int f32 = flags[0];
  if (idx < 57344) {
    const void* W; u16* Wf; int NCOLS, li;
    if (idx < 16384)      { W = W1; Wf = Wf1; NCOLS = 128; li = idx; }
    else if (idx < 32768) { W = W2; Wf = Wf2; NCOLS = 128; li = idx - 16384; }
    else                  { W = W3; Wf = Wf3; NCOLS = 188; li = idx - 32768; }
    int j = li & 7;
    int l = (li >> 3) & 63;
    int c = (li >> 9) & 3;
    int t = li >> 11;
    int k = c * 32 + (l >> 4) * 8 + j;
    int n = t * 16 + (l & 15);
    Wf[li] = (n < NCOLS) ? conv_elem(W, k * NCOLS + n, f32) : (u16)0;
  } else {
    int li = idx - 57344;
    const void* src; int off;
    if (li < 128)       { src = a1s; off = 16384; }
    else if (li < 256)  { src = a1d; off = 16512; li -= 128; }
    else if (li < 384)  { src = b1;  off = 16640; li -= 256; }
    else if (li < 512)  { src = a2s; off = 33152; li -= 384; }
    else if (li < 640)  { src = a2d; off = 33280; li -= 512; }
    else if (li < 768)  { src = b2;  off = 33408; li -= 640; }
    else if (li < 956)  { src = a3s; off = 57600; li -= 768; }
    else if (li < 1144) { src = a3d; off = 57788; li -= 956; }
    else if (li < 1191) { src = b3;  off = 57976; li -= 1144; }
    else return;
    wt[off + li] = conv_elem(src, li, f32);
  }
}

// ---------------- CSR build (NO global atomics) ----------------
// Coarse counting-sort by dst-bucket (256 nodes/bucket), all atomics in LDS:
//   pack_hist -> scan_cols -> scan_base -> scatter_coarse -> build_csr.
// Only csr_src32 + row_start survive (weights are computed in the aggregates).

// pass 1: pack (dst<<16)|src and per-block LDS histogram of dst>>8.
__global__ __launch_bounds__(256) void pack_hist(const int* __restrict__ ei,
                                                 const int* __restrict__ flags,
                                                 uint32* __restrict__ epack,
                                                 int* __restrict__ cnt, int nE) {
  __shared__ int hist[NB_BKT];
  for (int t = threadIdx.x; t < NB_BKT; t += 256) hist[t] = 0;
  __syncthreads();
  const int i64 = flags[1];
  const int chunk = (nE + NBH - 1) / NBH;
  const int lo = blockIdx.x * chunk;
  const int hi = min(lo + chunk, nE);
  for (int e = lo + (int)threadIdx.x; e < hi; e += 256) {
    int s = eget(ei, e, i64);
    int d = eget(ei, nE + e, i64);
    epack[e] = ((uint32)d << 16) | (uint32)s;
    atomicAdd(&hist[d >> 8], 1);
  }
  __syncthreads();
  for (int t = threadIdx.x; t < NB_BKT; t += 256) cnt[t * NBH + blockIdx.x] = hist[t];
}

// exclusive scan of cnt[bkt][0..NBH) along the block axis (in place) + bucket totals.
__global__ __launch_bounds__(256) void scan_cols(int* __restrict__ cnt,
                                                 int* __restrict__ total) {
  __shared__ int ws[4];
  const int bkt = blockIdx.x;
  const int tid = threadIdx.x, lane = tid & 63, wv = tid >> 6;
  int v = cnt[bkt * NBH + tid];
  int incl = v;
#pragma unroll
  for (int off = 1; off < 64; off <<= 1) {
    int t = __shfl_up(incl, off, 64);
    if (lane >= off) incl += t;
  }
  if (lane == 63) ws[wv] = incl;
  __syncthreads();
  if (tid == 0) {
    int s = 0;
#pragma unroll
    for (int w = 0; w < 4; w++) { int t = ws[w]; ws[w] = s; s += t; }
    total[bkt] = s;
  }
  __syncthreads();
  cnt[bkt * NBH + tid] = ws[wv] + incl - v;
}

// exclusive scan of the 196 bucket totals -> base[0..NB_BKT], base[NB_BKT]=nE.
__global__ __launch_bounds__(256) void scan_base(const int* __restrict__ total,
                                                 int* __restrict__ base) {
  __shared__ int ws[4];
  const int tid = threadIdx.x, lane = tid & 63, wv = tid >> 6;
  int v = (tid < NB_BKT) ? total[tid] : 0;
  int incl = v;
#pragma unroll
  for (int off = 1; off < 64; off <<= 1) {
    int t = __shfl_up(incl, off, 64);
    if (lane >= off) incl += t;
  }
  if (lane == 63) ws[wv] = incl;
  __syncthreads();
  if (tid == 0) {
    int s = 0;
#pragma unroll
    for (int w = 0; w < 4; w++) { int t = ws[w]; ws[w] = s; s += t; }
    base[NB_BKT] = s;
  }
  __syncthreads();
  if (tid < NB_BKT) base[tid] = ws[wv] + incl - v;
}

// pass 2: scatter into bucket-contiguous staging (per-(block,bucket) runs).
__global__ __launch_bounds__(256) void scatter_coarse(const uint32* __restrict__ epack,
                                                      const int* __restrict__ cnt,
                                                      const int* __restrict__ base,
                                                      uint32* __restrict__ staging, int nE) {
  __shared__ int lcur[NB_BKT];
  for (int t = threadIdx.x; t < NB_BKT; t += 256)
    lcur[t] = base[t] + cnt[t * NBH + blockIdx.x];
  __syncthreads();
  const int chunk = (nE + NBH - 1) / NBH;
  const int lo = blockIdx.x * chunk;
  const int hi = min(lo + chunk, nE);
  for (int e = lo + (int)threadIdx.x; e < hi; e += 256) {
    uint32 pk = epack[e];
    int p = atomicAdd(&lcur[pk >> 24], 1);  // bkt = d>>8 = pk>>24
    staging[p] = pk;
  }
}

// pass 3 (fused): per-bucket degree hist + scan + row_start + self-loop slot +
// edge placement, all into csr_src32. One block per bucket.
__global__ __launch_bounds__(256) void build_csr(const uint32* __restrict__ staging,
                                                 const int* __restrict__ base,
                                                 int* __restrict__ row_start,
                                                 int* __restrict__ csr_src32, int nN) {
  __shared__ int hist[256];
  __shared__ int cur[256];
  __shared__ int ws[4];
  const int b = blockIdx.x;
  const int tid = threadIdx.x;
  const int lane = tid & 63, wv = tid >> 6;
  hist[tid] = 0;
  __syncthreads();
  const int lo = base[b], hi = base[b + 1];
  for (int i = lo + tid; i < hi; i += 256)
    atomicAdd(&hist[(staging[i] >> 16) & 255], 1);
  __syncthreads();
  int v = hist[tid];
  int incl = v;
#pragma unroll
  for (int off = 1; off < 64; off <<= 1) {
    int t = __shfl_up(incl, off, 64);
    if (lane >= off) incl += t;
  }
  if (lane == 63) ws[wv] = incl;
  __syncthreads();
  if (tid == 0) {
    int s = 0;
#pragma unroll
    for (int w = 0; w < 4; w++) { int t = ws[w]; ws[w] = s; s += t; }
  }
  __syncthreads();
  int excl = ws[wv] + incl - v;
  const int n = (b << 8) + tid;
  if (n < nN) {
    int rs = lo + (b << 8) + excl + tid;  // edges-before + selfloops-before
    row_start[n] = rs;
    csr_src32[rs] = n;    // self-loop at slot rs
    cur[tid] = rs + 1;
  }
  if (b == NB_BKT - 1 && tid == 0) row_start[nN] = N_TOT;
  __syncthreads();
  for (int i = lo + tid; i < hi; i += 256) {
    uint32 pk = staging[i];
    int p = atomicAdd(&cur[(pk >> 16) & 255], 1);
    csr_src32[p] = (int)(pk & 0xffffu);
  }
}

// ---------------- MFMA GEMM: H[M,NCOLS] = X[M,128] @ W[128,NCOLS] ----------------
// One wave per 16-row tile. B from fragment-ordered Wf (L2-resident). No LDS.
// RAWX: A is the raw input x (fp32 or bf16 per flags[0]); conversion fused into
//       the fragment load (kills the convert_x4 pass).
// FUSE_A (layers 1/2): head h owns tiles 2h,2h+1 -> logits in epilogue.
// CMAJOR+FUSE3 (layer 3): class-major store, head-masked logit accumulation,
//       and bf16 1.0 written into pad cols 188..191 (the aggregate3 den column).
template <int NT, int NCOLS, int STRIDE, bool FUSE_A, bool CMAJOR, bool FUSE3, bool RAWX>
__global__ __launch_bounds__(256) void gemm_mfma(const void* __restrict__ X,
                                                 const u16* __restrict__ Wf,
                                                 const u16* __restrict__ attS,
                                                 const u16* __restrict__ attD,
                                                 const int* __restrict__ flags,
                                                 u16* __restrict__ H,
                                                 float* __restrict__ a_s,
                                                 float* __restrict__ a_d, int M) {
  // readfirstlane: prove wave-uniformity of the wave id to the compiler (SGPR loops/addrs)
  const int wid = __builtin_amdgcn_readfirstlane(threadIdx.x >> 6);
  const int lane = threadIdx.x & 63;
  const int row0 = (blockIdx.x * 4 + wid) * 16;
  if (row0 >= M) return;
  const int qr = lane >> 4;   // quad: k-subchunk for A/B, row group for C/D
  const int ln = lane & 15;   // A row within tile / C col within tile

  float4v acc[NT];
#pragma unroll
  for (int t = 0; t < NT; t++) acc[t] = (float4v){0.f, 0.f, 0.f, 0.f};

  const short8* Wf8 = (const short8*)Wf;  // [(t*4 + c)*64 + lane]
  const size_t aoff = (size_t)(row0 + ln) * 128 + qr * 8;
  int f32m = 0;
  if constexpr (RAWX) f32m = flags[0];

#pragma unroll
  for (int c = 0; c < 4; c++) {
    short8 afrag;
    if constexpr (RAWX) {
      if (f32m) {
        const float* ap = (const float*)X + aoff + c * 32;
        float4 lo = ((const float4*)ap)[0];
        float4 hi = ((const float4*)ap)[1];
        afrag[0] = (short)f2b(lo.x); afrag[1] = (short)f2b(lo.y);
        afrag[2] = (short)f2b(lo.z); afrag[3] = (short)f2b(lo.w);
        afrag[4] = (short)f2b(hi.x); afrag[5] = (short)f2b(hi.y);
        afrag[6] = (short)f2b(hi.z); afrag[7] = (short)f2b(hi.w);
      } else {
        afrag = *(const short8*)((const u16*)X + aoff + c * 32);
      }
    } else {
      afrag = *(const short8*)((const u16*)X + aoff + c * 32);
    }
#pragma unroll
    for (int t = 0; t < NT; t++) {
      short8 bfrag = Wf8[(t * 4 + c) * 64 + lane];
      acc[t] = __builtin_amdgcn_mfma_f32_16x16x32_bf16(afrag, bfrag, acc[t], 0, 0, 0);
    }
  }

  // store H (D layout: row = qr*4 + i, col = t*16 + ln)
#pragma unroll
  for (int t = 0; t < NT; t++) {
    int col = t * 16 + ln;
    if (col < NCOLS) {
      int off;
      if constexpr (CMAJOR) {
        int h = (col >= 141) ? 3 : (col >= 94) ? 2 : (col >= 47) ? 1 : 0;
        int c = col - h * 47;
        off = c * 4 + h;
      } else {
        off = col;
      }
#pragma unroll
      for (int i = 0; i < 4; i++) {
        H[(size_t)(row0 + qr * 4 + i) * STRIDE + off] = f2b(acc[t][i]);
      }
    } else {
      if constexpr (CMAJOR) {
        // pad cols 188..191: bf16 1.0 -> aggregate3's den pseudo-class (uint2 col 47)
#pragma unroll
        for (int i = 0; i < 4; i++) {
          H[(size_t)(row0 + qr * 4 + i) * STRIDE + col] = (u16)0x3F80;
        }
      }
    }
  }

  if constexpr (FUSE_A) {
    float aSf[NT], aDf[NT];
#pragma unroll
    for (int t = 0; t < NT; t++) {
      aSf[t] = b2f(attS[t * 16 + ln]);
      aDf[t] = b2f(attD[t * 16 + ln]);
    }
#pragma unroll
    for (int h = 0; h < 4; h++) {
#pragma unroll
      for (int i = 0; i < 4; i++) {
        float s = acc[2 * h][i] * aSf[2 * h] + acc[2 * h + 1][i] * aSf[2 * h + 1];
        float d = acc[2 * h][i] * aDf[2 * h] + acc[2 * h + 1][i] * aDf[2 * h + 1];
#pragma unroll
        for (int m = 1; m < 16; m <<= 1) {
          s += __shfl_xor(s, m, 64);
          d += __shfl_xor(d, m, 64);
        }
        if (ln == 0) {
          int r = row0 + qr * 4 + i;
          a_s[r * 4 + h] = s;
          a_d[r * 4 + h] = d;
        }
      }
    }
  }

  if constexpr (FUSE3) {
    // a_s[n][h] = sum_c H[n][h*47+c] * attS[h*47+c]; col = h*47+c indexes attS directly.
    float sh[4][4], dh[4][4];  // [head][i]
#pragma unroll
    for (int h = 0; h < 4; h++)
#pragma unroll
      for (int i = 0; i < 4; i++) { sh[h][i] = 0.f; dh[h][i] = 0.f; }
#pragma unroll
    for (int t = 0; t < NT; t++) {
      int col = t * 16 + ln;
      bool v = (col < NCOLS);
      float aS = v ? b2f(attS[col]) : 0.f;
      float aD = v ? b2f(attD[col]) : 0.f;
      int hh = (col >= 141) ? 3 : (col >= 94) ? 2 : (col >= 47) ? 1 : 0;
      float aS0 = (hh == 0) ? aS : 0.f, aS1 = (hh == 1) ? aS : 0.f;
      float aS2 = (hh == 2) ? aS : 0.f, aS3 = (hh == 3) ? aS : 0.f;
      float aD0 = (hh == 0) ? aD : 0.f, aD1 = (hh == 1) ? aD : 0.f;
      float aD2 = (hh == 2) ? aD : 0.f, aD3 = (hh == 3) ? aD : 0.f;
#pragma unroll
      for (int i = 0; i < 4; i++) {
        float a = acc[t][i];
        sh[0][i] += a * aS0; sh[1][i] += a * aS1;
        sh[2][i] += a * aS2; sh[3][i] += a * aS3;
        dh[0][i] += a * aD0; dh[1][i] += a * aD1;
        dh[2][i] += a * aD2; dh[3][i] += a * aD3;
      }
    }
#pragma unroll
    for (int h = 0; h < 4; h++) {
#pragma unroll
      for (int i = 0; i < 4; i++) {
        float s = sh[h][i], d = dh[h][i];
#pragma unroll
        for (int m = 1; m < 16; m <<= 1) {
          s += __shfl_xor(s, m, 64);
          d += __shfl_xor(d, m, 64);
        }
        if (ln == 0) {
          int r = row0 + qr * 4 + i;
          a_s[r * 4 + h] = s;
          a_d[r * 4 + h] = d;
        }
      }
    }
  }
}

// ---------------- aggregation (one node per wave; wave-uniform scalar metadata) ----------

// layers 1/2: lane L owns cols 2L,2L+1 (head L>>4). One uint gather/edge/lane.
// Edge weights computed INLINE (fp32, self-normalizing).
__global__ __launch_bounds__(256) void aggregate12(const u16* __restrict__ h,
                                                   const float* __restrict__ a_s,
                                                   const float* __restrict__ a_d,
                                                   const int* __restrict__ row_start,
                                                   const int* __restrict__ csr_src,
                                                   const u16* __restrict__ bias,
                                                   u16* __restrict__ out, int nN) {
  const int lane = threadIdx.x & 63;
  const int wid = __builtin_amdgcn_readfirstlane(threadIdx.x >> 6);  // SGPR wave id
  const int n = blockIdx.x * 4 + wid;
  if (n >= nN) return;
  const int hL = lane >> 4;  // head of cols 2L, 2L+1
  const uint32* h32 = (const uint32*)h;
  const float bias0 = b2f(bias[2 * lane]);
  const float bias1 = b2f(bias[2 * lane + 1]);
  const float adv = a_d[n * 4 + hL];  // wave-row uniform, per head group
  int beg = row_start[n], end = row_start[n + 1];

  float acc0 = 0.f, acc1 = 0.f, den = 0.f;
  int e = beg;
  for (; e + 3 < end; e += 4) {
    int s[4];
    float av[4];
    uint32 g[4];
#pragma unroll
    for (int j = 0; j < 4; j++) s[j] = csr_src[e + j];
#pragma unroll
    for (int j = 0; j < 4; j++) av[j] = a_s[s[j] * 4 + hL];
#pragma unroll
    for (int j = 0; j < 4; j++) g[j] = h32[s[j] * 64 + lane];
#pragma unroll
    for (int j = 0; j < 4; j++) {
      float w = __expf(lrelu(av[j] + adv));
      den += w;
      acc0 += w * lo_bf(g[j]);
      acc1 += w * hi_bf(g[j]);
    }
  }
  for (; e < end; ++e) {
    int s = csr_src[e];
    float w = __expf(lrelu(a_s[s * 4 + hL] + adv));
    uint32 g = h32[s * 64 + lane];
    den += w;
    acc0 += w * lo_bf(g);
    acc1 += w * hi_bf(g);
  }
  float inv = 1.0f / den;
  float o0 = fmaxf(acc0 * inv + bias0, 0.f);  // relu between layers
  float o1 = fmaxf(acc1 * inv + bias1, 0.f);
  uint32 packed = ((uint32)f2b(o1) << 16) | (uint32)f2b(o0);
  ((uint32*)out)[n * 64 + lane] = packed;
}

// layer 3: class-major h3 (uint2 gather = 4 head vals for class `lane`).
// Weights computed in idle lanes 48..63 (lane 48+4j+h -> w[edge j][head h]) and
// distributed via compile-time __shfl; den comes free from the ones pseudo-class
// (lidx 47) accumulated in lane 47. mean over heads + bias + log_softmax.
__global__ __launch_bounds__(256) void aggregate3(const u16* __restrict__ h3,
                                                  const float* __restrict__ a_s,
                                                  const float* __restrict__ a_d,
                                                  const int* __restrict__ row_start,
                                                  const int* __restrict__ csr_src,
                                                  const u16* __restrict__ b3,
                                                  const int* __restrict__ flags,
                                                  void* __restrict__ out, int nN) {
  const int lane = threadIdx.x & 63;
  const int wid = __builtin_amdgcn_readfirstlane(threadIdx.x >> 6);  // SGPR wave id
  const int n = blockIdx.x * 4 + wid;
  if (n >= nN) return;
  const bool act = lane < 47;
  const int lidx = (lane <= 47) ? lane : 0;  // lane 47 reads the ones-column -> den
  const float b3v = act ? b2f(b3[lane]) : 0.f;
  const int isf32 = flags[0];
  const uint2* h3v = (const uint2*)h3;  // row = 48 uint2
  const int wh = (lane - 48) & 3;                      // head for weight lanes
  const int lw = (lane >= 48) ? ((lane - 48) >> 2) : 0;  // edge slot for weight lanes
  const float advW = a_d[n * 4 + wh];
  int beg = row_start[n], end = row_start[n + 1];

  float acc0 = 0.f, acc1 = 0.f, acc2 = 0.f, acc3 = 0.f;
  int e = beg;
  for (; e + 7 < end; e += 8) {
    // weight lanes: wA covers edges e..e+3, wB covers e+4..e+7
    int sA = csr_src[e + lw];
    int sB = csr_src[e + 4 + lw];
    float wA = __expf(lrelu(a_s[sA * 4 + wh] + advW));
    float wB = __expf(lrelu(a_s[sB * 4 + wh] + advW));
    int s[8];
    uint2 g[8];
#pragma unroll
    for (int j = 0; j < 8; j++) s[j] = csr_src[e + j];
#pragma unroll
    for (int j = 0; j < 8; j++) g[j] = h3v[(size_t)s[j] * 48 + lidx];
#pragma unroll
    for (int j = 0; j < 8; j++) {
      const int bl = 48 + (j & 3) * 4;
      float w0, w1, w2, w3;
      if (j < 4) {
        w0 = __shfl(wA, bl + 0, 64); w1 = __shfl(wA, bl + 1, 64);
        w2 = __shfl(wA, bl + 2, 64); w3 = __shfl(wA, bl + 3, 64);
      } else {
        w0 = __shfl(wB, bl + 0, 64); w1 = __shfl(wB, bl + 1, 64);
        w2 = __shfl(wB, bl + 2, 64); w3 = __shfl(wB, bl + 3, 64);
      }
      acc0 += w0 * lo_bf(g[j].x);
      acc1 += w1 * hi_bf(g[j].x);
      acc2 += w2 * lo_bf(g[j].y);
      acc3 += w3 * hi_bf(g[j].y);
    }
  }
  for (; e < end; ++e) {
    int s = csr_src[e];  // wave-uniform
    float w = __expf(lrelu(a_s[s * 4 + wh] + advW));
    uint2 g = h3v[(size_t)s * 48 + lidx];
    float w0 = __shfl(w, 48, 64);
    float w1 = __shfl(w, 49, 64);
    float w2 = __shfl(w, 50, 64);
    float w3 = __shfl(w, 51, 64);
    acc0 += w0 * lo_bf(g.x);
    acc1 += w1 * hi_bf(g.x);
    acc2 += w2 * lo_bf(g.y);
    acc3 += w3 * hi_bf(g.y);
  }
  // dens live in lane 47's accumulators (w * 1.0 sums, same order as acc)
  float den0 = __shfl(acc0, 47, 64);
  float den1 = __shfl(acc1, 47, 64);
  float den2 = __shfl(acc2, 47, 64);
  float den3 = __shfl(acc3, 47, 64);
  float val = act ? 0.25f * (acc0 / den0 + acc1 / den1 + acc2 / den2 + acc3 / den3) + b3v
                  : -1e30f;
  float mx = val;
#pragma unroll
  for (int m = 1; m < 64; m <<= 1) mx = fmaxf(mx, __shfl_xor(mx, m, 64));
  float ex = act ? __expf(val - mx) : 0.f;
  float sm = ex;
#pragma unroll
  for (int m = 1; m < 64; m <<= 1) sm += __shfl_xor(sm, m, 64);
  float lse = mx + __logf(sm);
  if (act) {
    float r = val - lse;
    if (isf32) ((float*)out)[n * 47 + lane] = r;
    else       ((u16*)out)[n * 47 + lane] = f2b(r);
  }
}

// ---------------- launch ----------------

extern "C" void kernel_launch(void* const* d_in, const int* in_sizes, int n_in,
                              void* d_out, int out_size, void* d_ws, size_t ws_size,
                              hipStream_t stream) {
  const void* x   = d_in[0];
  const void* ei  = d_in[1];
  const void* W1  = d_in[2];
  const void* a1s = d_in[3];
  const void* a1d = d_in[4];
  const void* b1  = d_in[5];
  const void* W2  = d_in[6];
  const void* a2s = d_in[7];
  const void* a2d = d_in[8];
  const void* b2  = d_in[9];
  const void* W3  = d_in[10];
  const void* a3s = d_in[11];
  const void* a3d = d_in[12];
  const void* b3  = d_in[13];
  const int* ei32 = (const int*)ei;

  auto au = [](size_t v) { return (v + 255) & ~(size_t)255; };
  char* p = (char*)d_ws;
  int* flags     = (int*)p; p += 256;
  u16* wt        = (u16*)p; p += au((size_t)58023 * 2);
  u16* Wf1       = (u16*)p; p += au((size_t)16384 * 2);
  u16* Wf2       = (u16*)p; p += au((size_t)16384 * 2);
  u16* Wf3       = (u16*)p; p += au((size_t)24576 * 2);
  int* row_start = (int*)p; p += au((size_t)(N_NODES + 1) * 4);
  int* cnt       = (int*)p; p += au((size_t)NB_BKT * NBH * 4);
  int* btotal    = (int*)p; p += au((size_t)NB_BKT * 4);
  int* bbase     = (int*)p; p += au((size_t)(NB_BKT + 1) * 4);
  int* csr_src32 = (int*)p; p += au((size_t)N_TOT * 4);
  float* a_s     = (float*)p; p += au((size_t)N_NODES * 4 * 4);
  float* a_d     = (float*)p; p += au((size_t)N_NODES * 4 * 4);
  u16* hB        = (u16*)p; p += au((size_t)N_NODES * 128 * 2);
  u16* hA        = (u16*)p; p += au((size_t)N_NODES * 128 * 2);
  u16* h3        = (u16*)p; p += au((size_t)N_NODES * 192 * 2);
  // epack/staging alias h3: both consumed before layer 3 writes h3.
  uint32* epack   = (uint32*)h3;               // 3.2 MB
  uint32* staging = (uint32*)(h3 + 1600000);   // next 3.2 MB

  const u16* a1sc = wt + 16384;
  const u16* a1dc = wt + 16512;
  const u16* b1c  = wt + 16640;
  const u16* a2sc = wt + 33152;
  const u16* a2dc = wt + 33280;
  const u16* b2c  = wt + 33408;
  const u16* a3sc = wt + 57600;
  const u16* a3dc = wt + 57788;
  const u16* b3c  = wt + 57976;

  const int gemmBlocks = (N_NODES / 16 + 3) / 4;   // wave per 16-row tile: 782

  // dtype detection (fp32/bf16 floats, int64/int32 edges)
  detect_mode<<<1, 256, 0, stream>>>((const u16*)x, ei32, flags);
  reorder_all<<<229, 256, 0, stream>>>(W1, W2, W3, a1s, a1d, b1, a2s, a2d, b2,
                                       a3s, a3d, b3, flags, Wf1, Wf2, Wf3, wt);

  // CSR build: coarse counting-sort by dst bucket; LDS atomics only.
  pack_hist<<<NBH, 256, 0, stream>>>(ei32, flags, epack, cnt, N_EDGES);
  scan_cols<<<NB_BKT, 256, 0, stream>>>(cnt, btotal);
  scan_base<<<1, 256, 0, stream>>>(btotal, bbase);
  scatter_coarse<<<NBH, 256, 0, stream>>>(epack, cnt, bbase, staging, N_EDGES);
  build_csr<<<NB_BKT, 256, 0, stream>>>(staging, bbase, row_start, csr_src32, N_NODES);

  // layer 1 (x conversion fused into A-load; logits fused into GEMM epilogue;
  //          weights fused into aggregate)
  gemm_mfma<8, 128, 128, true, false, false, true><<<gemmBlocks, 256, 0, stream>>>(
      x, Wf1, a1sc, a1dc, flags, hA, a_s, a_d, N_NODES);
  aggregate12<<<NODE_BLOCKS, 256, 0, stream>>>(hA, a_s, a_d, row_start, csr_src32,
                                               b1c, hB, N_NODES);

  // layer 2
  gemm_mfma<8, 128, 128, true, false, false, false><<<gemmBlocks, 256, 0, stream>>>(
      hB, Wf2, a2sc, a2dc, flags, hA, a_s, a_d, N_NODES);
  aggregate12<<<NODE_BLOCKS, 256, 0, stream>>>(hA, a_s, a_d, row_start, csr_src32,
                                               b2c, hB, N_NODES);

  // layer 3 (h3 class-major + ones pad col; logits fused via head-masked reduce;
  //          weights + den fused into aggregate3)
  gemm_mfma<12, 188, 192, false, true, true, false><<<gemmBlocks, 256, 0, stream>>>(
      hB, Wf3, a3sc, a3dc, flags, h3, a_s, a_d, N_NODES);
  aggregate3<<<NODE_BLOCKS, 256, 0, stream>>>(h3, a_s, a_d, row_start, csr_src32,
                                              b3c, flags, d_out, N_NODES);
}

// Round 6
// 311.704 us; speedup vs baseline: 1.3088x; 1.0313x over previous
//
#include <hip/hip_runtime.h>

typedef unsigned short u16;
typedef unsigned int uint32;
typedef __attribute__((ext_vector_type(8))) short short8;
typedef __attribute__((ext_vector_type(4))) float float4v;

#define N_NODES 50000
#define N_EDGES 800000
#define N_TOT   850000
#define NBH 256                          // blocks for hist/scatter passes
#define NB_BKT ((N_NODES + 255) >> 8)    // 196 coarse dst-buckets (256 nodes each)
#define NODE_BLOCKS ((N_NODES + 3) / 4)  // 12500: one wave per node

__device__ __forceinline__ float b2f(u16 u) {
  return __uint_as_float(((unsigned int)u) << 16);
}
__device__ __forceinline__ u16 f2b(float f) {
  unsigned int x = __float_as_uint(f);
  unsigned int r = (x + 0x7fffu + ((x >> 16) & 1u)) >> 16;
  return (u16)r;
}
__device__ __forceinline__ float lo_bf(uint32 g) { return __uint_as_float(g << 16); }
__device__ __forceinline__ float hi_bf(uint32 g) { return __uint_as_float(g & 0xffff0000u); }
__device__ __forceinline__ u16 conv_elem(const void* src, int i, int isf32) {
  if (isf32) return f2b(((const float*)src)[i]);
  return ((const u16*)src)[i];
}
__device__ __forceinline__ float lrelu(float a) { return (a >= 0.f) ? a : 0.2f * a; }
// edge_index element i (flat [2,E]); int64 mode reads low word (ids < 2^31)
__device__ __forceinline__ int eget(const int* __restrict__ ei, int i, int isI64) {
  return isI64 ? ei[2 * i] : ei[i];
}

// ---------------- dtype detection ----------------
// flags[0]=1 if float inputs are fp32 (else bf16); flags[1]=1 if edge_index is int64.
__global__ void detect_mode(const u16* __restrict__ x16, const int* __restrict__ ei32,
                            int* __restrict__ flags) {
  __shared__ int sh_f32, sh_i32;
  int tid = threadIdx.x;
  if (tid == 0) { sh_f32 = 0; sh_i32 = 0; }
  __syncthreads();
  int emax = 0;
  for (int i = tid; i < 4096; i += 256) {
    int e = (x16[i] >> 7) & 0xFF;  // bf16 exponent field
    emax = emax > e ? emax : e;
  }
  if (emax >= 140) atomicOr(&sh_f32, 1);           // |v| >= 2^13: impossible for real bf16 N(0,1)
  if (ei32[2 * tid + 1] != 0) atomicOr(&sh_i32, 1); // nonzero odd word => int32 data
  __syncthreads();
  if (tid == 0) { flags[0] = sh_f32; flags[1] = sh_i32 ? 0 : 1; }
}

// ---------------- W fragment reorder (direct from raw inputs) + att/bias convert ----------
// Wf[t][c][lane][j] = W[c*32 + (lane>>4)*8 + j][t*16 + (lane&15)], zero-padded.
// Tail threads (idx >= 57344) convert the 1063 att/bias elements into wt.
__global__ void reorder_all(const void* W1, const void* W2, const void* W3,
                            const void* a1s, const void* a1d, const void* b1,
                            const void* a2s, const void* a2d, const void* b2,
                            const void* a3s, const void* a3d, const void* b3,
                            const int* __restrict__ flags,
                            u16* __restrict__ Wf1, u16* __restrict__ Wf2,
                            u16* __restrict__ Wf3, u16* __restrict__ wt) {
  int idx = blockIdx.x * blockDim.x + threadIdx.x;
  int f32 = flags[0];
  if (idx < 57344) {
    const void* W; u16* Wf; int NCOLS, li;
    if (idx < 16384)      { W = W1; Wf = Wf1; NCOLS = 128; li = idx; }
    else if (idx < 32768) { W = W2; Wf = Wf2; NCOLS = 128; li = idx - 16384; }
    else                  { W = W3; Wf = Wf3; NCOLS = 188; li = idx - 32768; }
    int j = li & 7;
    int l = (li >> 3) & 63;
    int c = (li >> 9) & 3;
    int t = li >> 11;
    int k = c * 32 + (l >> 4) * 8 + j;
    int n = t * 16 + (l & 15);
    Wf[li] = (n < NCOLS) ? conv_elem(W, k * NCOLS + n, f32) : (u16)0;
  } else {
    int li = idx - 57344;
    const void* src; int off;
    if (li < 128)       { src = a1s; off = 16384; }
    else if (li < 256)  { src = a1d; off = 16512; li -= 128; }
    else if (li < 384)  { src = b1;  off = 16640; li -= 256; }
    else if (li < 512)  { src = a2s; off = 33152; li -= 384; }
    else if (li < 640)  { src = a2d; off = 33280; li -= 512; }
    else if (li < 768)  { src = b2;  off = 33408; li -= 640; }
    else if (li < 956)  { src = a3s; off = 57600; li -= 768; }
    else if (li < 1144) { src = a3d; off = 57788; li -= 956; }
    else if (li < 1191) { src = b3;  off = 57976; li -= 1144; }
    else return;
    wt[off + li] = conv_elem(src, li, f32);
  }
}

// ---------------- CSR build (NO global atomics) ----------------
// Coarse counting-sort by dst-bucket (256 nodes/bucket), all atomics in LDS:
//   pack_hist -> scan_cols -> scan_base -> scatter_coarse -> build_csr.

// pass 1: pack (dst<<16)|src and per-block LDS histogram of dst>>8.
__global__ __launch_bounds__(256) void pack_hist(const int* __restrict__ ei,
                                                 const int* __restrict__ flags,
                                                 uint32* __restrict__ epack,
                                                 int* __restrict__ cnt, int nE) {
  __shared__ int hist[NB_BKT];
  for (int t = threadIdx.x; t < NB_BKT; t += 256) hist[t] = 0;
  __syncthreads();
  const int i64 = flags[1];
  const int chunk = (nE + NBH - 1) / NBH;
  const int lo = blockIdx.x * chunk;
  const int hi = min(lo + chunk, nE);
  for (int e = lo + (int)threadIdx.x; e < hi; e += 256) {
    int s = eget(ei, e, i64);
    int d = eget(ei, nE + e, i64);
    epack[e] = ((uint32)d << 16) | (uint32)s;
    atomicAdd(&hist[d >> 8], 1);
  }
  __syncthreads();
  for (int t = threadIdx.x; t < NB_BKT; t += 256) cnt[t * NBH + blockIdx.x] = hist[t];
}

// exclusive scan of cnt[bkt][0..NBH) along the block axis (in place) + bucket totals.
__global__ __launch_bounds__(256) void scan_cols(int* __restrict__ cnt,
                                                 int* __restrict__ total) {
  __shared__ int ws[4];
  const int bkt = blockIdx.x;
  const int tid = threadIdx.x, lane = tid & 63, wv = tid >> 6;
  int v = cnt[bkt * NBH + tid];
  int incl = v;
#pragma unroll
  for (int off = 1; off < 64; off <<= 1) {
    int t = __shfl_up(incl, off, 64);
    if (lane >= off) incl += t;
  }
  if (lane == 63) ws[wv] = incl;
  __syncthreads();
  if (tid == 0) {
    int s = 0;
#pragma unroll
    for (int w = 0; w < 4; w++) { int t = ws[w]; ws[w] = s; s += t; }
    total[bkt] = s;
  }
  __syncthreads();
  cnt[bkt * NBH + tid] = ws[wv] + incl - v;
}

// exclusive scan of the 196 bucket totals -> base[0..NB_BKT], base[NB_BKT]=nE.
__global__ __launch_bounds__(256) void scan_base(const int* __restrict__ total,
                                                 int* __restrict__ base) {
  __shared__ int ws[4];
  const int tid = threadIdx.x, lane = tid & 63, wv = tid >> 6;
  int v = (tid < NB_BKT) ? total[tid] : 0;
  int incl = v;
#pragma unroll
  for (int off = 1; off < 64; off <<= 1) {
    int t = __shfl_up(incl, off, 64);
    if (lane >= off) incl += t;
  }
  if (lane == 63) ws[wv] = incl;
  __syncthreads();
  if (tid == 0) {
    int s = 0;
#pragma unroll
    for (int w = 0; w < 4; w++) { int t = ws[w]; ws[w] = s; s += t; }
    base[NB_BKT] = s;
  }
  __syncthreads();
  if (tid < NB_BKT) base[tid] = ws[wv] + incl - v;
}

// pass 2: scatter into bucket-contiguous staging (per-(block,bucket) runs).
__global__ __launch_bounds__(256) void scatter_coarse(const uint32* __restrict__ epack,
                                                      const int* __restrict__ cnt,
                                                      const int* __restrict__ base,
                                                      uint32* __restrict__ staging, int nE) {
  __shared__ int lcur[NB_BKT];
  for (int t = threadIdx.x; t < NB_BKT; t += 256)
    lcur[t] = base[t] + cnt[t * NBH + blockIdx.x];
  __syncthreads();
  const int chunk = (nE + NBH - 1) / NBH;
  const int lo = blockIdx.x * chunk;
  const int hi = min(lo + chunk, nE);
  for (int e = lo + (int)threadIdx.x; e < hi; e += 256) {
    uint32 pk = epack[e];
    int p = atomicAdd(&lcur[pk >> 24], 1);  // bkt = d>>8 = pk>>24
    staging[p] = pk;
  }
}

// pass 3 (fused): per-bucket degree hist + scan + row_start + self-loop slot +
// csr_dst runs + edge placement. One block per bucket.
__global__ __launch_bounds__(256) void build_csr(const uint32* __restrict__ staging,
                                                 const int* __restrict__ base,
                                                 int* __restrict__ row_start,
                                                 u16* __restrict__ csr_dst,
                                                 int* __restrict__ csr_src32, int nN) {
  __shared__ int hist[256];
  __shared__ int cur[256];
  __shared__ int ws[4];
  const int b = blockIdx.x;
  const int tid = threadIdx.x;
  const int lane = tid & 63, wv = tid >> 6;
  hist[tid] = 0;
  __syncthreads();
  const int lo = base[b], hi = base[b + 1];
  for (int i = lo + tid; i < hi; i += 256)
    atomicAdd(&hist[(staging[i] >> 16) & 255], 1);
  __syncthreads();
  int v = hist[tid];
  int incl = v;
#pragma unroll
  for (int off = 1; off < 64; off <<= 1) {
    int t = __shfl_up(incl, off, 64);
    if (lane >= off) incl += t;
  }
  if (lane == 63) ws[wv] = incl;
  __syncthreads();
  if (tid == 0) {
    int s = 0;
#pragma unroll
    for (int w = 0; w < 4; w++) { int t = ws[w]; ws[w] = s; s += t; }
  }
  __syncthreads();
  int excl = ws[wv] + incl - v;
  const int n = (b << 8) + tid;
  if (n < nN) {
    int rs = lo + (b << 8) + excl + tid;  // edges-before + selfloops-before
    row_start[n] = rs;
    csr_src32[rs] = n;    // self-loop at slot rs
    u16 g16 = (u16)n;
    for (int k = 0; k <= v; k++) csr_dst[rs + k] = g16;
    cur[tid] = rs + 1;
  }
  if (b == NB_BKT - 1 && tid == 0) row_start[nN] = N_TOT;
  __syncthreads();
  for (int i = lo + tid; i < hi; i += 256) {
    uint32 pk = staging[i];
    int p = atomicAdd(&cur[(pk >> 16) & 255], 1);
    csr_src32[p] = (int)(pk & 0xffffu);
  }
}

// ---------------- MFMA GEMM: H[M,NCOLS] = X[M,128] @ W[128,NCOLS] ----------------
// One wave per 16-row tile. B from fragment-ordered Wf (L2-resident). No LDS.
// RAWX: A is the raw input x (fp32 or bf16 per flags[0]); conversion fused into
//       the fragment load (kills the convert_x4 pass).
// FUSE_A (layers 1/2): head h owns tiles 2h,2h+1 -> logits in epilogue.
// CMAJOR+FUSE3 (layer 3): class-major store, head-masked logit accumulation,
//       and bf16 1.0 written into pad cols 188..191 (the aggregate3 den column).
template <int NT, int NCOLS, int STRIDE, bool FUSE_A, bool CMAJOR, bool FUSE3, bool RAWX>
__global__ __launch_bounds__(256) void gemm_mfma(const void* __restrict__ X,
                                                 const u16* __restrict__ Wf,
                                                 const u16* __restrict__ attS,
                                                 const u16* __restrict__ attD,
                                                 const int* __restrict__ flags,
                                                 u16* __restrict__ H,
                                                 float* __restrict__ a_s,
                                                 float* __restrict__ a_d, int M) {
  // readfirstlane: prove wave-uniformity of the wave id to the compiler (SGPR loops/addrs)
  const int wid = __builtin_amdgcn_readfirstlane(threadIdx.x >> 6);
  const int lane = threadIdx.x & 63;
  const int row0 = (blockIdx.x * 4 + wid) * 16;
  if (row0 >= M) return;
  const int qr = lane >> 4;   // quad: k-subchunk for A/B, row group for C/D
  const int ln = lane & 15;   // A row within tile / C col within tile

  float4v acc[NT];
#pragma unroll
  for (int t = 0; t < NT; t++) acc[t] = (float4v){0.f, 0.f, 0.f, 0.f};

  const short8* Wf8 = (const short8*)Wf;  // [(t*4 + c)*64 + lane]
  const size_t aoff = (size_t)(row0 + ln) * 128 + qr * 8;
  int f32m = 0;
  if constexpr (RAWX) f32m = flags[0];

#pragma unroll
  for (int c = 0; c < 4; c++) {
    short8 afrag;
    if constexpr (RAWX) {
      if (f32m) {
        const float* ap = (const float*)X + aoff + c * 32;
        float4 lo = ((const float4*)ap)[0];
        float4 hi = ((const float4*)ap)[1];
        afrag[0] = (short)f2b(lo.x); afrag[1] = (short)f2b(lo.y);
        afrag[2] = (short)f2b(lo.z); afrag[3] = (short)f2b(lo.w);
        afrag[4] = (short)f2b(hi.x); afrag[5] = (short)f2b(hi.y);
        afrag[6] = (short)f2b(hi.z); afrag[7] = (short)f2b(hi.w);
      } else {
        afrag = *(const short8*)((const u16*)X + aoff + c * 32);
      }
    } else {
      afrag = *(const short8*)((const u16*)X + aoff + c * 32);
    }
#pragma unroll
    for (int t = 0; t < NT; t++) {
      short8 bfrag = Wf8[(t * 4 + c) * 64 + lane];
      acc[t] = __builtin_amdgcn_mfma_f32_16x16x32_bf16(afrag, bfrag, acc[t], 0, 0, 0);
    }
  }

  // store H (D layout: row = qr*4 + i, col = t*16 + ln)
#pragma unroll
  for (int t = 0; t < NT; t++) {
    int col = t * 16 + ln;
    if (col < NCOLS) {
      int off;
      if constexpr (CMAJOR) {
        int h = (col >= 141) ? 3 : (col >= 94) ? 2 : (col >= 47) ? 1 : 0;
        int c = col - h * 47;
        off = c * 4 + h;
      } else {
        off = col;
      }
#pragma unroll
      for (int i = 0; i < 4; i++) {
        H[(size_t)(row0 + qr * 4 + i) * STRIDE + off] = f2b(acc[t][i]);
      }
    } else {
      if constexpr (CMAJOR) {
        // pad cols 188..191: bf16 1.0 -> aggregate3's den pseudo-class (uint2 col 47)
#pragma unroll
        for (int i = 0; i < 4; i++) {
          H[(size_t)(row0 + qr * 4 + i) * STRIDE + col] = (u16)0x3F80;
        }
      }
    }
  }

  if constexpr (FUSE_A) {
    float aSf[NT], aDf[NT];
#pragma unroll
    for (int t = 0; t < NT; t++) {
      aSf[t] = b2f(attS[t * 16 + ln]);
      aDf[t] = b2f(attD[t * 16 + ln]);
    }
#pragma unroll
    for (int h = 0; h < 4; h++) {
#pragma unroll
      for (int i = 0; i < 4; i++) {
        float s = acc[2 * h][i] * aSf[2 * h] + acc[2 * h + 1][i] * aSf[2 * h + 1];
        float d = acc[2 * h][i] * aDf[2 * h] + acc[2 * h + 1][i] * aDf[2 * h + 1];
#pragma unroll
        for (int m = 1; m < 16; m <<= 1) {
          s += __shfl_xor(s, m, 64);
          d += __shfl_xor(d, m, 64);
        }
        if (ln == 0) {
          int r = row0 + qr * 4 + i;
          a_s[r * 4 + h] = s;
          a_d[r * 4 + h] = d;
        }
      }
    }
  }

  if constexpr (FUSE3) {
    // a_s[n][h] = sum_c H[n][h*47+c] * attS[h*47+c]; col = h*47+c indexes attS directly.
    float sh[4][4], dh[4][4];  // [head][i]
#pragma unroll
    for (int h = 0; h < 4; h++)
#pragma unroll
      for (int i = 0; i < 4; i++) { sh[h][i] = 0.f; dh[h][i] = 0.f; }
#pragma unroll
    for (int t = 0; t < NT; t++) {
      int col = t * 16 + ln;
      bool v = (col < NCOLS);
      float aS = v ? b2f(attS[col]) : 0.f;
      float aD = v ? b2f(attD[col]) : 0.f;
      int hh = (col >= 141) ? 3 : (col >= 94) ? 2 : (col >= 47) ? 1 : 0;
      float aS0 = (hh == 0) ? aS : 0.f, aS1 = (hh == 1) ? aS : 0.f;
      float aS2 = (hh == 2) ? aS : 0.f, aS3 = (hh == 3) ? aS : 0.f;
      float aD0 = (hh == 0) ? aD : 0.f, aD1 = (hh == 1) ? aD : 0.f;
      float aD2 = (hh == 2) ? aD : 0.f, aD3 = (hh == 3) ? aD : 0.f;
#pragma unroll
      for (int i = 0; i < 4; i++) {
        float a = acc[t][i];
        sh[0][i] += a * aS0; sh[1][i] += a * aS1;
        sh[2][i] += a * aS2; sh[3][i] += a * aS3;
        dh[0][i] += a * aD0; dh[1][i] += a * aD1;
        dh[2][i] += a * aD2; dh[3][i] += a * aD3;
      }
    }
#pragma unroll
    for (int h = 0; h < 4; h++) {
#pragma unroll
      for (int i = 0; i < 4; i++) {
        float s = sh[h][i], d = dh[h][i];
#pragma unroll
        for (int m = 1; m < 16; m <<= 1) {
          s += __shfl_xor(s, m, 64);
          d += __shfl_xor(d, m, 64);
        }
        if (ln == 0) {
          int r = row0 + qr * 4 + i;
          a_s[r * 4 + h] = s;
          a_d[r * 4 + h] = d;
        }
      }
    }
  }
}

// ---------------- per-edge softmax weights for layer 3 (unnormalized, packed bf16x4) ----
// w[e][h] = exp(leaky(a_s[src][h] + a_d[dst][h])) as bf16. Self-normalizing: den sums
// the same bf16 values (via the ones pseudo-class), so ratios carry ~2^-9 rel error.
__global__ __launch_bounds__(256) void edge_weights(const int* __restrict__ csr_src,
                                                    const u16* __restrict__ csr_dst,
                                                    const float* __restrict__ a_s,
                                                    const float* __restrict__ a_d,
                                                    uint2* __restrict__ w, int nE) {
  int e = blockIdx.x * blockDim.x + threadIdx.x;
  if (e >= nE) return;
  int s = csr_src[e], d = csr_dst[e];
  float4 as = ((const float4*)a_s)[s];
  float4 ad = ((const float4*)a_d)[d];
  float w0 = __expf(lrelu(as.x + ad.x));
  float w1 = __expf(lrelu(as.y + ad.y));
  float w2 = __expf(lrelu(as.z + ad.z));
  float w3 = __expf(lrelu(as.w + ad.w));
  uint2 o;
  o.x = ((uint32)f2b(w1) << 16) | (uint32)f2b(w0);
  o.y = ((uint32)f2b(w3) << 16) | (uint32)f2b(w2);
  w[e] = o;
}

// ---------------- aggregation (one node per wave; wave-uniform scalar metadata) ----------

// layers 1/2: lane L owns cols 2L,2L+1 (head L>>4). One uint gather/edge/lane.
// Edge weights computed INLINE (fp32, per-lane independent -> no shuffles).
__global__ __launch_bounds__(256) void aggregate12(const u16* __restrict__ h,
                                                   const float* __restrict__ a_s,
                                                   const float* __restrict__ a_d,
                                                   const int* __restrict__ row_start,
                                                   const int* __restrict__ csr_src,
                                                   const u16* __restrict__ bias,
                                                   u16* __restrict__ out, int nN) {
  const int lane = threadIdx.x & 63;
  const int wid = __builtin_amdgcn_readfirstlane(threadIdx.x >> 6);  // SGPR wave id
  const int n = blockIdx.x * 4 + wid;
  if (n >= nN) return;
  const int hL = lane >> 4;  // head of cols 2L, 2L+1
  const uint32* h32 = (const uint32*)h;
  const float bias0 = b2f(bias[2 * lane]);
  const float bias1 = b2f(bias[2 * lane + 1]);
  const float adv = a_d[n * 4 + hL];  // wave-row uniform, per head group
  int beg = row_start[n], end = row_start[n + 1];

  float acc0 = 0.f, acc1 = 0.f, den = 0.f;
  int e = beg;
  for (; e + 3 < end; e += 4) {
    int s[4];
    float av[4];
    uint32 g[4];
#pragma unroll
    for (int j = 0; j < 4; j++) s[j] = csr_src[e + j];
#pragma unroll
    for (int j = 0; j < 4; j++) av[j] = a_s[s[j] * 4 + hL];
#pragma unroll
    for (int j = 0; j < 4; j++) g[j] = h32[s[j] * 64 + lane];
#pragma unroll
    for (int j = 0; j < 4; j++) {
      float w = __expf(lrelu(av[j] + adv));
      den += w;
      acc0 += w * lo_bf(g[j]);
      acc1 += w * hi_bf(g[j]);
    }
  }
  for (; e < end; ++e) {
    int s = csr_src[e];
    float w = __expf(lrelu(a_s[s * 4 + hL] + adv));
    uint32 g = h32[s * 64 + lane];
    den += w;
    acc0 += w * lo_bf(g);
    acc1 += w * hi_bf(g);
  }
  float inv = 1.0f / den;
  float o0 = fmaxf(acc0 * inv + bias0, 0.f);  // relu between layers
  float o1 = fmaxf(acc1 * inv + bias1, 0.f);
  uint32 packed = ((uint32)f2b(o1) << 16) | (uint32)f2b(o0);
  ((uint32*)out)[n * 64 + lane] = packed;
}

// layer 3: class-major h3 (uint2 gather = 4 head vals for class `lane`).
// Weights from the precomputed wbuf (wave-uniform broadcast load, no shuffles
// in the loop); den comes free from the ones pseudo-class accumulated in
// lane 47. mean over heads + bias + log_softmax.
__global__ __launch_bounds__(256) void aggregate3(const u16* __restrict__ h3,
                                                  const uint2* __restrict__ wbuf,
                                                  const int* __restrict__ row_start,
                                                  const int* __restrict__ csr_src,
                                                  const u16* __restrict__ b3,
                                                  const int* __restrict__ flags,
                                                  void* __restrict__ out, int nN) {
  const int lane = threadIdx.x & 63;
  const int wid = __builtin_amdgcn_readfirstlane(threadIdx.x >> 6);  // SGPR wave id
  const int n = blockIdx.x * 4 + wid;
  if (n >= nN) return;
  const bool act = lane < 47;
  const int lidx = (lane <= 47) ? lane : 0;  // lane 47 reads the ones-column -> den
  const float b3v = act ? b2f(b3[lane]) : 0.f;
  const int isf32 = flags[0];
  const uint2* h3v = (const uint2*)h3;  // row = 48 uint2
  int beg = row_start[n], end = row_start[n + 1];

  float acc0 = 0.f, acc1 = 0.f, acc2 = 0.f, acc3 = 0.f;
  int e = beg;
  for (; e + 7 < end; e += 8) {
    int s[8];
    uint2 wp[8];
    uint2 g[8];
#pragma unroll
    for (int j = 0; j < 8; j++) s[j] = csr_src[e + j];
#pragma unroll
    for (int j = 0; j < 8; j++) wp[j] = wbuf[e + j];
#pragma unroll
    for (int j = 0; j < 8; j++) g[j] = h3v[(size_t)s[j] * 48 + lidx];
#pragma unroll
    for (int j = 0; j < 8; j++) {
      float w0 = lo_bf(wp[j].x), w1 = hi_bf(wp[j].x);
      float w2 = lo_bf(wp[j].y), w3 = hi_bf(wp[j].y);
      acc0 += w0 * lo_bf(g[j].x);
      acc1 += w1 * hi_bf(g[j].x);
      acc2 += w2 * lo_bf(g[j].y);
      acc3 += w3 * hi_bf(g[j].y);
    }
  }
  for (; e + 3 < end; e += 4) {
    int s[4];
    uint2 wp[4];
    uint2 g[4];
#pragma unroll
    for (int j = 0; j < 4; j++) s[j] = csr_src[e + j];
#pragma unroll
    for (int j = 0; j < 4; j++) wp[j] = wbuf[e + j];
#pragma unroll
    for (int j = 0; j < 4; j++) g[j] = h3v[(size_t)s[j] * 48 + lidx];
#pragma unroll
    for (int j = 0; j < 4; j++) {
      float w0 = lo_bf(wp[j].x), w1 = hi_bf(wp[j].x);
      float w2 = lo_bf(wp[j].y), w3 = hi_bf(wp[j].y);
      acc0 += w0 * lo_bf(g[j].x);
      acc1 += w1 * hi_bf(g[j].x);
      acc2 += w2 * lo_bf(g[j].y);
      acc3 += w3 * hi_bf(g[j].y);
    }
  }
  for (; e < end; ++e) {
    int s = csr_src[e];
    uint2 wp = wbuf[e];
    uint2 g = h3v[(size_t)s * 48 + lidx];
    float w0 = lo_bf(wp.x), w1 = hi_bf(wp.x);
    float w2 = lo_bf(wp.y), w3 = hi_bf(wp.y);
    acc0 += w0 * lo_bf(g.x);
    acc1 += w1 * hi_bf(g.x);
    acc2 += w2 * lo_bf(g.y);
    acc3 += w3 * hi_bf(g.y);
  }
  // dens live in lane 47's accumulators (w * 1.0 sums, same add order as r4's den)
  float den0 = __shfl(acc0, 47, 64);
  float den1 = __shfl(acc1, 47, 64);
  float den2 = __shfl(acc2, 47, 64);
  float den3 = __shfl(acc3, 47, 64);
  float val = act ? 0.25f * (acc0 / den0 + acc1 / den1 + acc2 / den2 + acc3 / den3) + b3v
                  : -1e30f;
  float mx = val;
#pragma unroll
  for (int m = 1; m < 64; m <<= 1) mx = fmaxf(mx, __shfl_xor(mx, m, 64));
  float ex = act ? __expf(val - mx) : 0.f;
  float sm = ex;
#pragma unroll
  for (int m = 1; m < 64; m <<= 1) sm += __shfl_xor(sm, m, 64);
  float lse = mx + __logf(sm);
  if (act) {
    float r = val - lse;
    if (isf32) ((float*)out)[n * 47 + lane] = r;
    else       ((u16*)out)[n * 47 + lane] = f2b(r);
  }
}

// ---------------- launch ----------------

extern "C" void kernel_launch(void* const* d_in, const int* in_sizes, int n_in,
                              void* d_out, int out_size, void* d_ws, size_t ws_size,
                              hipStream_t stream) {
  const void* x   = d_in[0];
  const void* ei  = d_in[1];
  const void* W1  = d_in[2];
  const void* a1s = d_in[3];
  const void* a1d = d_in[4];
  const void* b1  = d_in[5];
  const void* W2  = d_in[6];
  const void* a2s = d_in[7];
  const void* a2d = d_in[8];
  const void* b2  = d_in[9];
  const void* W3  = d_in[10];
  const void* a3s = d_in[11];
  const void* a3d = d_in[12];
  const void* b3  = d_in[13];
  const int* ei32 = (const int*)ei;

  auto au = [](size_t v) { return (v + 255) & ~(size_t)255; };
  char* p = (char*)d_ws;
  int* flags     = (int*)p; p += 256;
  u16* wt        = (u16*)p; p += au((size_t)58023 * 2);
  u16* Wf1       = (u16*)p; p += au((size_t)16384 * 2);
  u16* Wf2       = (u16*)p; p += au((size_t)16384 * 2);
  u16* Wf3       = (u16*)p; p += au((size_t)24576 * 2);
  int* row_start = (int*)p; p += au((size_t)(N_NODES + 1) * 4);
  int* cnt       = (int*)p; p += au((size_t)NB_BKT * NBH * 4);
  int* btotal    = (int*)p; p += au((size_t)NB_BKT * 4);
  int* bbase     = (int*)p; p += au((size_t)(NB_BKT + 1) * 4);
  int* csr_src32 = (int*)p; p += au((size_t)N_TOT * 4);
  u16* csr_dst   = (u16*)p; p += au((size_t)N_TOT * 2);
  uint2* wbuf    = (uint2*)p; p += au((size_t)N_TOT * 8);
  float* a_s     = (float*)p; p += au((size_t)N_NODES * 4 * 4);
  float* a_d     = (float*)p; p += au((size_t)N_NODES * 4 * 4);
  u16* hB        = (u16*)p; p += au((size_t)N_NODES * 128 * 2);
  u16* hA        = (u16*)p; p += au((size_t)N_NODES * 128 * 2);
  u16* h3        = (u16*)p; p += au((size_t)N_NODES * 192 * 2);
  // epack/staging alias h3: both consumed before layer 3 writes h3.
  uint32* epack   = (uint32*)h3;               // 3.2 MB
  uint32* staging = (uint32*)(h3 + 1600000);   // next 3.2 MB

  const u16* a1sc = wt + 16384;
  const u16* a1dc = wt + 16512;
  const u16* b1c  = wt + 16640;
  const u16* a2sc = wt + 33152;
  const u16* a2dc = wt + 33280;
  const u16* b2c  = wt + 33408;
  const u16* a3sc = wt + 57600;
  const u16* a3dc = wt + 57788;
  const u16* b3c  = wt + 57976;

  const int gemmBlocks = (N_NODES / 16 + 3) / 4;   // wave per 16-row tile: 782
  const int edgeBlocks = (N_TOT + 255) / 256;

  // dtype detection (fp32/bf16 floats, int64/int32 edges)
  detect_mode<<<1, 256, 0, stream>>>((const u16*)x, ei32, flags);
  reorder_all<<<229, 256, 0, stream>>>(W1, W2, W3, a1s, a1d, b1, a2s, a2d, b2,
                                       a3s, a3d, b3, flags, Wf1, Wf2, Wf3, wt);

  // CSR build: coarse counting-sort by dst bucket; LDS atomics only.
  pack_hist<<<NBH, 256, 0, stream>>>(ei32, flags, epack, cnt, N_EDGES);
  scan_cols<<<NB_BKT, 256, 0, stream>>>(cnt, btotal);
  scan_base<<<1, 256, 0, stream>>>(btotal, bbase);
  scatter_coarse<<<NBH, 256, 0, stream>>>(epack, cnt, bbase, staging, N_EDGES);
  build_csr<<<NB_BKT, 256, 0, stream>>>(staging, bbase, row_start, csr_dst,
                                        csr_src32, N_NODES);

  // layer 1 (x conversion fused into A-load; logits fused into GEMM epilogue;
  //          weights fused into aggregate)
  gemm_mfma<8, 128, 128, true, false, false, true><<<gemmBlocks, 256, 0, stream>>>(
      x, Wf1, a1sc, a1dc, flags, hA, a_s, a_d, N_NODES);
  aggregate12<<<NODE_BLOCKS, 256, 0, stream>>>(hA, a_s, a_d, row_start, csr_src32,
                                               b1c, hB, N_NODES);

  // layer 2
  gemm_mfma<8, 128, 128, true, false, false, false><<<gemmBlocks, 256, 0, stream>>>(
      hB, Wf2, a2sc, a2dc, flags, hA, a_s, a_d, N_NODES);
  aggregate12<<<NODE_BLOCKS, 256, 0, stream>>>(hA, a_s, a_d, row_start, csr_src32,
                                               b2c, hB, N_NODES);

  // layer 3 (h3 class-major + ones pad col; logits fused via head-masked reduce;
  //          weights precomputed per edge; den from the ones pseudo-class)
  gemm_mfma<12, 188, 192, false, true, true, false><<<gemmBlocks, 256, 0, stream>>>(
      hB, Wf3, a3sc, a3dc, flags, h3, a_s, a_d, N_NODES);
  edge_weights<<<edgeBlocks, 256, 0, stream>>>(csr_src32, csr_dst, a_s, a_d, wbuf, N_TOT);
  aggregate3<<<NODE_BLOCKS, 256, 0, stream>>>(h3, wbuf, row_start, csr_src32,
                                              b3c, flags, d_out, N_NODES);
}